// Round 12
// baseline (177.877 us; speedup 1.0000x reference)
//
#include <hip/hip_runtime.h>
#include <hip/hip_bf16.h>
#include <hip/hip_fp8.h>

#define N_NODES 50000
#define N_EDGES 800000
#define HB 3125   // hist/scatter blocks: 800000/256
#define GB1 1563  // gemm1 blocks: ceil(50000/32)
#define NBS 49    // scan blocks: ceil(50000/1024)

static constexpr float SCALE = 0.17677669529663687f; // 1/sqrt(32)

typedef __attribute__((ext_vector_type(8))) short bf16x8;
typedef __attribute__((ext_vector_type(4))) float f32x4;
typedef __attribute__((ext_vector_type(2))) float f32x2;
#define MFMA16 __builtin_amdgcn_mfma_f32_16x16x32_bf16
#define CVT8 __builtin_amdgcn_cvt_pk_f32_fp8

static __device__ inline unsigned short f2bf(float f) {
    __hip_bfloat16 h = __float2bfloat16(f);
    return __builtin_bit_cast(unsigned short, h);
}
static __device__ inline unsigned char f2fp8(float f) {
    __hip_fp8_e4m3 h(f); // OCP e4m3fn, RNE
    return __builtin_bit_cast(unsigned char, h);
}
// packed pair of bf16 (one u32) -> f32x2
static __device__ inline f32x2 bfp2(unsigned u) {
    f32x2 r;
    r[0] = __uint_as_float(u << 16);
    r[1] = __uint_as_float(u & 0xffff0000u);
    return r;
}
static __device__ inline bf16x8 cvt8(const float* p) {
    float4 f0 = *(const float4*)p;
    float4 f1 = *(const float4*)(p + 4);
    bf16x8 r;
    r[0] = (short)f2bf(f0.x); r[1] = (short)f2bf(f0.y);
    r[2] = (short)f2bf(f0.z); r[3] = (short)f2bf(f0.w);
    r[4] = (short)f2bf(f1.x); r[5] = (short)f2bf(f1.y);
    r[6] = (short)f2bf(f1.z); r[7] = (short)f2bf(f1.w);
    return r;
}

// ---------------- D1: hist (blocks 0..HB) || weight fragments (blocks HB..HB+192) ----------------
// Fragment convention (consistent for A and B, so exact HW k-order is irrelevant):
//   lane l, elem j  <->  k = ks*32 + (l>>4)*8 + j ;  col = nt*16 + (l&15)

__global__ __launch_bounds__(256) void k_ph(
    const int* __restrict__ dst, int* __restrict__ cnt, int* __restrict__ rank,
    const float* __restrict__ Wq1, const float* __restrict__ Wk1,
    const float* __restrict__ Wv1, const float* __restrict__ Ws1,
    const float* __restrict__ Wq2, const float* __restrict__ Wk2,
    const float* __restrict__ Wv2, const float* __restrict__ Ws2,
    unsigned short* __restrict__ Wf1, unsigned short* __restrict__ Wf2)
{
    if (blockIdx.x < HB) {
        int e = blockIdx.x * 256 + threadIdx.x; // E exact multiple of 256
        rank[e] = atomicAdd(&cnt[dst[e]], 1);
        return;
    }
    int id = (blockIdx.x - HB) * 256 + threadIdx.x;
    if (id < 32768) {
        int j = id & 7, l = (id >> 3) & 63, ks = (id >> 9) & 1, nt = (id >> 10) & 7, m = (id >> 13) & 3;
        const float* W = (m == 0) ? Wq1 : (m == 1) ? Wk1 : (m == 2) ? Wv1 : Ws1;
        int k = ks * 32 + ((l >> 4) << 3) + j;
        int c = nt * 16 + (l & 15);
        Wf1[id] = f2bf(W[k * 128 + c]);
    } else if (id < 49152) {
        int id2 = id - 32768;
        int j = id2 & 7, l = (id2 >> 3) & 63, ks = (id2 >> 9) & 3, g = (id2 >> 11) & 7;
        int m = g >> 1, t = g & 1;
        const float* W = (m == 0) ? Wq2 : (m == 1) ? Wk2 : (m == 2) ? Wv2 : Ws2;
        int k = ks * 32 + ((l >> 4) << 3) + j;
        int c = t * 16 + (l & 15);
        Wf2[id2] = f2bf(W[k * 32 + c]);
    }
}

// ---------------- D2: GEMM1 (blocks 0..GB1) || scan (blocks GB1..GB1+NBS) ----------------
// GEMM1 (MFMA): x[N,64]f32 (converted in-reg) @ {Wq,Wk,Wv,Ws}[64,128] + b
// outputs: qs1[N][256] bf16 (q 0:128, s 128:256);
//          kv8[N][256 bytes] fp8 interleaved: group w (0..15): k ch w*8..+8 at byte w*16, v at w*16+8.

__global__ __launch_bounds__(256) void k_gs(
    const int* __restrict__ cnt, int* __restrict__ row, int* __restrict__ bsum,
    int* __restrict__ boff, int* __restrict__ ctr,
    const float* __restrict__ x, const unsigned short* __restrict__ Wf1,
    const float* __restrict__ bq, const float* __restrict__ bk,
    const float* __restrict__ bv, const float* __restrict__ bs,
    unsigned short* __restrict__ qs1, unsigned char* __restrict__ kv8, int n)
{
    __shared__ unsigned char smem[4 * 4352]; // per-wave: bf16 [16][136] or fp8 [16][144]
    if (blockIdx.x >= GB1) {
        // ---- scan half ----
        __shared__ int wsum[4];
        __shared__ int lastBlk;
        int b = blockIdx.x - GB1;
        int t = threadIdx.x;
        int base = b * 1024 + t * 4;
        int v0 = (base + 0 < n) ? cnt[base + 0] : 0;
        int v1i = (base + 1 < n) ? cnt[base + 1] : 0;
        int v2 = (base + 2 < n) ? cnt[base + 2] : 0;
        int v3 = (base + 3 < n) ? cnt[base + 3] : 0;
        int s = v0 + v1i + v2 + v3;
        int lane = t & 63, wid = t >> 6;
        int sc = s;
#pragma unroll
        for (int d = 1; d < 64; d <<= 1) {
            int o = __shfl_up(sc, d);
            if (lane >= d) sc += o;
        }
        if (lane == 63) wsum[wid] = sc;
        __syncthreads();
        int woff = 0;
        for (int w = 0; w < wid; ++w) woff += wsum[w];
        int excl = woff + sc - s;
        if (base + 0 < n) row[base + 0] = excl;
        if (base + 1 < n) row[base + 1] = excl + v0;
        if (base + 2 < n) row[base + 2] = excl + v0 + v1i;
        if (base + 3 < n) row[base + 3] = excl + v0 + v1i + v2;
        if (t == 255) {
            bsum[b] = woff + sc;
            __threadfence();
            lastBlk = (atomicAdd(ctr, 1) == NBS - 1);
        }
        __syncthreads();
        if (lastBlk && t < 64) {
            __threadfence();
            int v = (t < NBS) ? ((volatile int*)bsum)[t] : 0;
            int sc2 = v;
#pragma unroll
            for (int d = 1; d < 64; d <<= 1) {
                int o = __shfl_up(sc2, d);
                if (t >= d) sc2 += o;
            }
            boff[t] = sc2 - v; // exclusive block offset
            if (t == (N_NODES >> 10)) row[N_NODES] = N_EDGES - (sc2 - v);
        }
        return;
    }
    // ---- gemm half ----
    int w = threadIdx.x >> 6;
    int l = threadIdx.x & 63;
    int rb = blockIdx.x * 32;
    int lr = l & 15, lk = l >> 4;
    f32x4 acc[2][8];
#pragma unroll
    for (int mt = 0; mt < 2; ++mt)
#pragma unroll
        for (int nt = 0; nt < 8; ++nt) acc[mt][nt] = (f32x4){0.f, 0.f, 0.f, 0.f};
#pragma unroll
    for (int ks = 0; ks < 2; ++ks) {
        bf16x8 a[2];
#pragma unroll
        for (int mt = 0; mt < 2; ++mt) {
            int r = rb + mt * 16 + lr;
            if (r >= n) r = n - 1;
            a[mt] = cvt8(x + (size_t)r * 64 + ks * 32 + lk * 8);
        }
#pragma unroll
        for (int nt = 0; nt < 8; ++nt) {
            bf16x8 b = *(const bf16x8*)(Wf1 + (size_t)((w * 8 + nt) * 1024 + ks * 512 + l * 8));
            acc[0][nt] = MFMA16(a[0], b, acc[0][nt], 0, 0, 0);
            acc[1][nt] = MFMA16(a[1], b, acc[1][nt], 0, 0, 0);
        }
    }
    const float* bptr = (w == 0) ? bq : (w == 1) ? bk : (w == 2) ? bv : bs;
    unsigned char* my = smem + w * 4352;
#pragma unroll
    for (int mt = 0; mt < 2; ++mt) {
        if (w == 1 || w == 2) { // k,v -> fp8 into interleaved kv8
            unsigned char* lb = my; // [16][144]
#pragma unroll
            for (int nt = 0; nt < 8; ++nt) {
                float bias = bptr[nt * 16 + lr];
#pragma unroll
                for (int i = 0; i < 4; ++i)
                    lb[(lk * 4 + i) * 144 + nt * 16 + lr] = f2fp8(acc[mt][nt][i] + bias);
            }
            int voff = (w == 2) ? 8 : 0; // v occupies the upper 8B of each 16B group
#pragma unroll
            for (int p = 0; p < 4; ++p) {
                int rl = p * 4 + lk;
                int r = rb + mt * 16 + rl;
                if (r < n) {
                    uint2 val = *(const uint2*)(lb + rl * 144 + lr * 8);
                    *(uint2*)(kv8 + (size_t)r * 256 + lr * 16 + voff) = val;
                }
            }
        } else {
            unsigned short* ls = (unsigned short*)my; // [16][136]
#pragma unroll
            for (int nt = 0; nt < 8; ++nt) {
                float bias = bptr[nt * 16 + lr];
#pragma unroll
                for (int i = 0; i < 4; ++i)
                    ls[(lk * 4 + i) * 136 + nt * 16 + lr] = f2bf(acc[mt][nt][i] + bias);
            }
            unsigned short* outp = (w == 0) ? qs1 : qs1 + 128;
#pragma unroll
            for (int p = 0; p < 4; ++p) {
                int rl = p * 4 + lk;
                int r = rb + mt * 16 + rl;
                if (r < n) {
                    uint4 val = *(const uint4*)(ls + rl * 136 + lr * 8);
                    *(uint4*)(outp + (size_t)r * 256 + lr * 8) = val;
                }
            }
        }
    }
}

// ---------------- scatter ----------------

__global__ void k_scat(const int* __restrict__ src, const int* __restrict__ dst,
                       const int* __restrict__ row, const int* __restrict__ boff,
                       const int* __restrict__ rank, int* __restrict__ col) {
    int e = blockIdx.x * 256 + threadIdx.x;
    int de = dst[e];
    col[row[de] + boff[de >> 10] + rank[e]] = src[e];
}

// ---------------- GEMM 2 (MFMA): h1b[N,128]bf16 @ {Wq,Wk,Wv,Ws}[128,32] + b ----------------
// LDS-staged epilogue; outputs: qs2[N][64] bf16 (q 0:32, s 32:64);
//                               k82[N][32] fp8; v2[N][32] bf16

__global__ __launch_bounds__(256) void k_gemm2m(
    const unsigned short* __restrict__ h1b, const unsigned short* __restrict__ Wf2,
    const float* __restrict__ bq, const float* __restrict__ bk,
    const float* __restrict__ bv, const float* __restrict__ bs,
    unsigned short* __restrict__ qs2, unsigned char* __restrict__ k82,
    unsigned short* __restrict__ v2, int n)
{
    __shared__ unsigned short lds[4][32][72]; // 18.4 KB
    int w = threadIdx.x >> 6;
    int l = threadIdx.x & 63;
    int half = w & 1;
    int rb = blockIdx.x * 64 + (w >> 1) * 32;
    int lr = l & 15, lk = l >> 4;
    f32x4 acc[2][4];
#pragma unroll
    for (int mt = 0; mt < 2; ++mt)
#pragma unroll
        for (int nt = 0; nt < 4; ++nt) acc[mt][nt] = (f32x4){0.f, 0.f, 0.f, 0.f};
#pragma unroll
    for (int ks = 0; ks < 4; ++ks) {
        bf16x8 a[2];
#pragma unroll
        for (int mt = 0; mt < 2; ++mt) {
            int r = rb + mt * 16 + lr;
            if (r >= n) r = n - 1;
            a[mt] = *(const bf16x8*)(h1b + (size_t)r * 128 + ks * 32 + lk * 8);
        }
#pragma unroll
        for (int nt = 0; nt < 4; ++nt) {
            int g = half * 4 + nt;
            bf16x8 b = *(const bf16x8*)(Wf2 + (size_t)((g * 4 + ks) * 512 + l * 8));
            acc[0][nt] = MFMA16(a[0], b, acc[0][nt], 0, 0, 0);
            acc[1][nt] = MFMA16(a[1], b, acc[1][nt], 0, 0, 0);
        }
    }
    // stage: half==0 waves hold q (lds cols 0..31) + k (32..63);
    //        half==1 waves hold v (0..31) + s (32..63)
#pragma unroll
    for (int nt = 0; nt < 4; ++nt) {
        int g = half * 4 + nt;
        int mat = g >> 1;
        int c = (g * 16 + lr) & 31;
        const float* bp = (mat == 0) ? bq : (mat == 1) ? bk : (mat == 2) ? bv : bs;
        float bias = bp[c];
#pragma unroll
        for (int mt = 0; mt < 2; ++mt)
#pragma unroll
            for (int i = 0; i < 4; ++i)
                lds[w][mt * 16 + lk * 4 + i][nt * 16 + lr] = f2bf(acc[mt][nt][i] + bias);
    }
    int rl8 = l >> 3, ci = (l & 7) * 4;
#pragma unroll
    for (int p = 0; p < 4; ++p) {
        int rl = p * 8 + rl8;
        int r = rb + rl;
        if (r < n) {
            uint2 va = *(const uint2*)&lds[w][rl][ci];
            uint2 vb = *(const uint2*)&lds[w][rl][32 + ci];
            if (half == 0) {
                *(uint2*)(qs2 + (size_t)r * 64 + ci) = va;              // q bf16
                unsigned pk =                                            // k -> fp8
                      (unsigned)f2fp8(__uint_as_float(vb.x << 16))
                    | ((unsigned)f2fp8(__uint_as_float(vb.x & 0xffff0000u)) << 8)
                    | ((unsigned)f2fp8(__uint_as_float(vb.y << 16)) << 16)
                    | ((unsigned)f2fp8(__uint_as_float(vb.y & 0xffff0000u)) << 24);
                *(unsigned*)(k82 + (size_t)r * 32 + ci) = pk;
            } else {
                *(uint2*)(v2 + (size_t)r * 32 + ci) = va;               // v bf16
                *(uint2*)(qs2 + (size_t)r * 64 + 32 + ci) = vb;         // s bf16
            }
        }
    }
}

// ---------------- Layer-1 attention aggregate ----------------
// one wave per dst node; lane = slot(0-3)*16 + w(0-15); lane owns channels [w*8, w*8+8).
// 16 edges per iteration: 4 independent dwordx4 gathers in flight per lane
// (latency-bound regime -> more MLP).

__global__ __launch_bounds__(256) void k_agg1(
    const unsigned short* __restrict__ qs1, const unsigned char* __restrict__ kv8,
    const int* __restrict__ row, const int* __restrict__ boff,
    const int* __restrict__ col, uint4* __restrict__ h1b, int n)
{
    int i = blockIdx.x * 4 + (threadIdx.x >> 6);
    if (i >= n) return;
    int lane = threadIdx.x & 63;
    int slot = lane >> 4, w = lane & 15;
    f32x2 q2[4];
    {
        uint4 qu = *(const uint4*)(qs1 + (size_t)i * 256 + w * 8);
        q2[0] = bfp2(qu.x); q2[1] = bfp2(qu.y); q2[2] = bfp2(qu.z); q2[3] = bfp2(qu.w);
    }
    f32x2 acc2[4] = {};
    float d = 0.f;
    int s = row[i] + boff[i >> 10];
    int e = row[i + 1] + boff[(i + 1) >> 10];
    for (int t = s; t < e; t += 16) {
        int t0 = t + slot, t1 = t + 4 + slot, t2 = t + 8 + slot, t3 = t + 12 + slot;
        bool u0 = t0 < e, u1 = t1 < e, u2 = t2 < e, u3 = t3 < e;
        int j0 = col[u0 ? t0 : s];
        int j1 = col[u1 ? t1 : s];
        int j2 = col[u2 ? t2 : s];
        int j3 = col[u3 ? t3 : s];
        uint4 A = *(const uint4*)(kv8 + (size_t)j0 * 256 + w * 16);
        uint4 B = *(const uint4*)(kv8 + (size_t)j1 * 256 + w * 16);
        uint4 C = *(const uint4*)(kv8 + (size_t)j2 * 256 + w * 16);
        uint4 D = *(const uint4*)(kv8 + (size_t)j3 * 256 + w * 16);
        f32x2 p0 = CVT8(A.x, false) * q2[0];
        p0 += CVT8(A.x, true)  * q2[1];
        p0 += CVT8(A.y, false) * q2[2];
        p0 += CVT8(A.y, true)  * q2[3];
        f32x2 p1 = CVT8(B.x, false) * q2[0];
        p1 += CVT8(B.x, true)  * q2[1];
        p1 += CVT8(B.y, false) * q2[2];
        p1 += CVT8(B.y, true)  * q2[3];
        f32x2 p2 = CVT8(C.x, false) * q2[0];
        p2 += CVT8(C.x, true)  * q2[1];
        p2 += CVT8(C.y, false) * q2[2];
        p2 += CVT8(C.y, true)  * q2[3];
        f32x2 p3 = CVT8(D.x, false) * q2[0];
        p3 += CVT8(D.x, true)  * q2[1];
        p3 += CVT8(D.y, false) * q2[2];
        p3 += CVT8(D.y, true)  * q2[3];
        float l0 = p0[0] + p0[1], l1 = p1[0] + p1[1];
        float l2 = p2[0] + p2[1], l3 = p3[0] + p3[1];
        l0 += __shfl_xor(l0, 1);  l1 += __shfl_xor(l1, 1);
        l2 += __shfl_xor(l2, 1);  l3 += __shfl_xor(l3, 1);
        l0 += __shfl_xor(l0, 2);  l1 += __shfl_xor(l1, 2);
        l2 += __shfl_xor(l2, 2);  l3 += __shfl_xor(l3, 2);
        float w0 = u0 ? __expf(l0 * SCALE) : 0.f;
        float w1 = u1 ? __expf(l1 * SCALE) : 0.f;
        float w2 = u2 ? __expf(l2 * SCALE) : 0.f;
        float w3 = u3 ? __expf(l3 * SCALE) : 0.f;
        d += (w0 + w1) + (w2 + w3);
        f32x2 w02 = (f32x2){w0, w0};
        f32x2 w12 = (f32x2){w1, w1};
        f32x2 w22 = (f32x2){w2, w2};
        f32x2 w32 = (f32x2){w3, w3};
        acc2[0] += w02 * CVT8(A.z, false);
        acc2[1] += w02 * CVT8(A.z, true);
        acc2[2] += w02 * CVT8(A.w, false);
        acc2[3] += w02 * CVT8(A.w, true);
        acc2[0] += w12 * CVT8(B.z, false);
        acc2[1] += w12 * CVT8(B.z, true);
        acc2[2] += w12 * CVT8(B.w, false);
        acc2[3] += w12 * CVT8(B.w, true);
        acc2[0] += w22 * CVT8(C.z, false);
        acc2[1] += w22 * CVT8(C.z, true);
        acc2[2] += w22 * CVT8(C.w, false);
        acc2[3] += w22 * CVT8(C.w, true);
        acc2[0] += w32 * CVT8(D.z, false);
        acc2[1] += w32 * CVT8(D.z, true);
        acc2[2] += w32 * CVT8(D.w, false);
        acc2[3] += w32 * CVT8(D.w, true);
    }
    float acc[8] = {acc2[0][0], acc2[0][1], acc2[1][0], acc2[1][1],
                    acc2[2][0], acc2[2][1], acc2[3][0], acc2[3][1]};
#pragma unroll
    for (int m = 16; m <= 32; m <<= 1) {
        d += __shfl_xor(d, m);
#pragma unroll
        for (int c = 0; c < 8; ++c) acc[c] += __shfl_xor(acc[c], m);
    }
    if (slot == 0) {
        float inv = (d > 0.f) ? 1.f / d : 0.f;
        uint4 su = *(const uint4*)(qs1 + (size_t)i * 256 + 128 + w * 8);
        f32x2 sv[4] = {bfp2(su.x), bfp2(su.y), bfp2(su.z), bfp2(su.w)};
        unsigned o[4];
#pragma unroll
        for (int p = 0; p < 4; ++p) {
            float rx = acc[2 * p] * inv + sv[p][0];
            float ry = acc[2 * p + 1] * inv + sv[p][1];
            rx = (rx > 0.f) ? rx : expm1f(rx); // ELU
            ry = (ry > 0.f) ? ry : expm1f(ry);
            o[p] = ((unsigned)f2bf(ry) << 16) | (unsigned)f2bf(rx);
        }
        h1b[(size_t)i * 16 + w] = make_uint4(o[0], o[1], o[2], o[3]);
    }
}

// ---------------- Layer-2 attention aggregate ----------------
// one wave per dst node; lane = slot(0-15)*4 + qr(0-3); 16 edges/iteration.
// k gathered as fp8 (8B/lane), v as bf16 (16B/lane).

__global__ __launch_bounds__(256) void k_agg2(
    const unsigned short* __restrict__ qs2, const unsigned char* __restrict__ k82,
    const unsigned short* __restrict__ v2,
    const int* __restrict__ row, const int* __restrict__ boff,
    const int* __restrict__ col, float* __restrict__ out, int n)
{
    int i = blockIdx.x * 4 + (threadIdx.x >> 6);
    if (i >= n) return;
    int lane = threadIdx.x & 63;
    int slot = lane >> 2, qr = lane & 3;
    f32x2 q2[4];
    {
        uint4 qu = *(const uint4*)(qs2 + (size_t)i * 64 + qr * 8);
        q2[0] = bfp2(qu.x); q2[1] = bfp2(qu.y); q2[2] = bfp2(qu.z); q2[3] = bfp2(qu.w);
    }
    f32x2 acc2[4] = {};
    float d = 0.f;
    int s = row[i] + boff[i >> 10];
    int e = row[i + 1] + boff[(i + 1) >> 10];
    for (int t = s; t < e; t += 16) {
        int te = t + slot;
        bool va = te < e;
        int j = col[va ? te : s];
        uint2 ku = *(const uint2*)(k82 + (size_t)j * 32 + qr * 8);
        uint4 vu = *(const uint4*)(v2 + (size_t)j * 32 + qr * 8);
        f32x2 pp = CVT8(ku.x, false) * q2[0];
        pp += CVT8(ku.x, true)  * q2[1];
        pp += CVT8(ku.y, false) * q2[2];
        pp += CVT8(ku.y, true)  * q2[3];
        float lg = pp[0] + pp[1];
        lg += __shfl_xor(lg, 1);
        lg += __shfl_xor(lg, 2);
        float wv = va ? __expf(lg * SCALE) : 0.f;
        d += wv;
        f32x2 w2 = (f32x2){wv, wv};
        acc2[0] += w2 * bfp2(vu.x);
        acc2[1] += w2 * bfp2(vu.y);
        acc2[2] += w2 * bfp2(vu.z);
        acc2[3] += w2 * bfp2(vu.w);
    }
    float acc[8] = {acc2[0][0], acc2[0][1], acc2[1][0], acc2[1][1],
                    acc2[2][0], acc2[2][1], acc2[3][0], acc2[3][1]};
#pragma unroll
    for (int m = 4; m <= 32; m <<= 1) {
        d += __shfl_xor(d, m);
#pragma unroll
        for (int c = 0; c < 8; ++c) acc[c] += __shfl_xor(acc[c], m);
    }
    if (slot == 0) {
        float inv = (d > 0.f) ? 1.f / d : 0.f;
        uint4 su = *(const uint4*)(qs2 + (size_t)i * 64 + 32 + qr * 8);
        f32x2 sv[4] = {bfp2(su.x), bfp2(su.y), bfp2(su.z), bfp2(su.w)};
        float4 o0, o1;
        o0.x = acc[0] * inv + sv[0][0];
        o0.y = acc[1] * inv + sv[0][1];
        o0.z = acc[2] * inv + sv[1][0];
        o0.w = acc[3] * inv + sv[1][1];
        o1.x = acc[4] * inv + sv[2][0];
        o1.y = acc[5] * inv + sv[2][1];
        o1.z = acc[6] * inv + sv[3][0];
        o1.w = acc[7] * inv + sv[3][1];
        *(float4*)&out[(size_t)i * 32 + qr * 8] = o0;
        *(float4*)&out[(size_t)i * 32 + qr * 8 + 4] = o1;
    }
}

// ---------------- launch ----------------

extern "C" void kernel_launch(void* const* d_in, const int* in_sizes, int n_in,
                              void* d_out, int out_size, void* d_ws, size_t ws_size,
                              hipStream_t stream)
{
    const int N = N_NODES, E = N_EDGES;
    const float* x   = (const float*)d_in[0];
    const int* edge  = (const int*)d_in[1];
    const int* src   = edge;       // edge_index[0]
    const int* dst   = edge + E;   // edge_index[1]
    const float* Wq1 = (const float*)d_in[2];  const float* bq1 = (const float*)d_in[3];
    const float* Wk1 = (const float*)d_in[4];  const float* bk1 = (const float*)d_in[5];
    const float* Wv1 = (const float*)d_in[6];  const float* bv1 = (const float*)d_in[7];
    const float* Ws1 = (const float*)d_in[8];  const float* bs1 = (const float*)d_in[9];
    const float* Wq2 = (const float*)d_in[10]; const float* bq2 = (const float*)d_in[11];
    const float* Wk2 = (const float*)d_in[12]; const float* bk2 = (const float*)d_in[13];
    const float* Wv2 = (const float*)d_in[14]; const float* bv2 = (const float*)d_in[15];
    const float* Ws2 = (const float*)d_in[16]; const float* bs2 = (const float*)d_in[17];

    char* ws = (char*)d_ws;
    size_t off = 0;
    auto alloc = [&](size_t bytes) -> void* {
        void* p = ws + off;
        off += (bytes + 255) & ~(size_t)255;
        return p;
    };
    unsigned short* qs1 = (unsigned short*)alloc((size_t)N * 256 * 2); // 25.6 MB
    unsigned char*  kv8 = (unsigned char*)alloc((size_t)N * 256);      // 12.8 MB (k,v interleaved fp8)
    unsigned short* h1b = (unsigned short*)alloc((size_t)N * 128 * 2); // 12.8 MB
    unsigned short* qs2 = (unsigned short*)alloc((size_t)N * 64 * 2);  //  6.4 MB
    unsigned char*  k82 = (unsigned char*)alloc((size_t)N * 32);       //  1.6 MB (fp8 k2)
    unsigned short* v2  = (unsigned short*)alloc((size_t)N * 32 * 2);  //  3.2 MB (bf16 v2)
    unsigned short* Wf1 = (unsigned short*)alloc(32768 * 2);
    unsigned short* Wf2 = (unsigned short*)alloc(16384 * 2);
    int* row_ptr  = (int*)alloc((size_t)(N + 1) * 4);
    int* cnt      = (int*)alloc((size_t)(N + 64) * 4); // cnt[N] + ctr
    int* ctr      = cnt + N;
    int* rank     = (int*)alloc((size_t)E * 4);
    int* colb     = (int*)alloc((size_t)E * 4);
    int* bsum     = (int*)alloc(64 * 4);
    int* boff     = (int*)alloc(64 * 4);

    hipMemsetAsync(cnt, 0, (size_t)(N + 64) * 4, stream);
    k_ph<<<HB + 192, 256, 0, stream>>>(dst, cnt, rank,
                                       Wq1, Wk1, Wv1, Ws1, Wq2, Wk2, Wv2, Ws2,
                                       Wf1, Wf2);
    k_gs<<<GB1 + NBS, 256, 0, stream>>>(cnt, row_ptr, bsum, boff, ctr,
                                        x, Wf1, bq1, bk1, bv1, bs1, qs1, kv8, N);
    k_scat<<<HB, 256, 0, stream>>>(src, dst, row_ptr, boff, rank, colb);
    k_agg1<<<(N + 3) / 4, 256, 0, stream>>>(qs1, kv8, row_ptr, boff, colb, (uint4*)h1b, N);
    k_gemm2m<<<(N + 63) / 64, 256, 0, stream>>>(h1b, Wf2, bq2, bk2, bv2, bs2, qs2, k82, v2, N);
    k_agg2<<<(N + 3) / 4, 256, 0, stream>>>(qs2, k82, v2, row_ptr, boff, colb, (float*)d_out, N);
}

// Round 13
// 157.246 us; speedup vs baseline: 1.1312x; 1.1312x over previous
//
#include <hip/hip_runtime.h>
#include <hip/hip_bf16.h>
#include <hip/hip_fp8.h>

#define N_NODES 50000
#define N_EDGES 800000
#define HB 3125   // hist/scatter blocks: 800000/256
#define GB1 1563  // gemm1 blocks: ceil(50000/32)
#define NBS 49    // scan blocks: ceil(50000/1024)

static constexpr float SCALE = 0.17677669529663687f; // 1/sqrt(32)

typedef __attribute__((ext_vector_type(8))) short bf16x8;
typedef __attribute__((ext_vector_type(4))) float f32x4;
typedef __attribute__((ext_vector_type(2))) float f32x2;
#define MFMA16 __builtin_amdgcn_mfma_f32_16x16x32_bf16
#define CVT8 __builtin_amdgcn_cvt_pk_f32_fp8

static __device__ inline unsigned short f2bf(float f) {
    __hip_bfloat16 h = __float2bfloat16(f);
    return __builtin_bit_cast(unsigned short, h);
}
static __device__ inline unsigned char f2fp8(float f) {
    __hip_fp8_e4m3 h(f); // OCP e4m3fn, RNE
    return __builtin_bit_cast(unsigned char, h);
}
// packed pair of bf16 (one u32) -> f32x2
static __device__ inline f32x2 bfp2(unsigned u) {
    f32x2 r;
    r[0] = __uint_as_float(u << 16);
    r[1] = __uint_as_float(u & 0xffff0000u);
    return r;
}

// ---------------- D1: hist (blocks 0..HB) || weight fragments (blocks HB..HB+192) ----------------
// Fragment convention (consistent for A and B, so exact HW k-order is irrelevant):
//   lane l, elem j  <->  k = ks*32 + (l>>4)*8 + j ;  col = nt*16 + (l&15)

__global__ __launch_bounds__(256) void k_ph(
    const int* __restrict__ dst, int* __restrict__ cnt, int* __restrict__ rank,
    const float* __restrict__ Wq1, const float* __restrict__ Wk1,
    const float* __restrict__ Wv1, const float* __restrict__ Ws1,
    const float* __restrict__ Wq2, const float* __restrict__ Wk2,
    const float* __restrict__ Wv2, const float* __restrict__ Ws2,
    unsigned short* __restrict__ Wf1, unsigned short* __restrict__ Wf2)
{
    if (blockIdx.x < HB) {
        int e = blockIdx.x * 256 + threadIdx.x; // E exact multiple of 256
        rank[e] = atomicAdd(&cnt[dst[e]], 1);
        return;
    }
    int id = (blockIdx.x - HB) * 256 + threadIdx.x;
    if (id < 32768) {
        int j = id & 7, l = (id >> 3) & 63, ks = (id >> 9) & 1, nt = (id >> 10) & 7, m = (id >> 13) & 3;
        const float* W = (m == 0) ? Wq1 : (m == 1) ? Wk1 : (m == 2) ? Wv1 : Ws1;
        int k = ks * 32 + ((l >> 4) << 3) + j;
        int c = nt * 16 + (l & 15);
        Wf1[id] = f2bf(W[k * 128 + c]);
    } else if (id < 49152) {
        int id2 = id - 32768;
        int j = id2 & 7, l = (id2 >> 3) & 63, ks = (id2 >> 9) & 3, g = (id2 >> 11) & 7;
        int m = g >> 1, t = g & 1;
        const float* W = (m == 0) ? Wq2 : (m == 1) ? Wk2 : (m == 2) ? Wv2 : Ws2;
        int k = ks * 32 + ((l >> 4) << 3) + j;
        int c = t * 16 + (l & 15);
        Wf2[id2] = f2bf(W[k * 32 + c]);
    }
}

// ---------------- D2: GEMM1 (blocks 0..GB1) || scan (blocks GB1..GB1+NBS) ----------------
// GEMM1 (MFMA): x[N,64]f32 staged ONCE per block into LDS as bf16, then
// all 4 waves read fragments via ds_read (removes 4x redundant global x reads).
// outputs: qs1[N][256] bf16 (q 0:128, s 128:256);
//          kv8[N][256 bytes] fp8 interleaved: group w (0..15): k ch w*8..+8 at byte w*16, v at w*16+8.

__global__ __launch_bounds__(256) void k_gs(
    const int* __restrict__ cnt, int* __restrict__ row, int* __restrict__ bsum,
    int* __restrict__ boff, int* __restrict__ ctr,
    const float* __restrict__ x, const unsigned short* __restrict__ Wf1,
    const float* __restrict__ bq, const float* __restrict__ bk,
    const float* __restrict__ bv, const float* __restrict__ bs,
    unsigned short* __restrict__ qs1, unsigned char* __restrict__ kv8, int n)
{
    __shared__ unsigned char smem[4 * 4352]; // union: xs[32][72]bf16 (4.6KB) then epilogue 4x4352B
    if (blockIdx.x >= GB1) {
        // ---- scan half ----
        __shared__ int wsum[4];
        __shared__ int lastBlk;
        int b = blockIdx.x - GB1;
        int t = threadIdx.x;
        int base = b * 1024 + t * 4;
        int v0 = (base + 0 < n) ? cnt[base + 0] : 0;
        int v1i = (base + 1 < n) ? cnt[base + 1] : 0;
        int v2 = (base + 2 < n) ? cnt[base + 2] : 0;
        int v3 = (base + 3 < n) ? cnt[base + 3] : 0;
        int s = v0 + v1i + v2 + v3;
        int lane = t & 63, wid = t >> 6;
        int sc = s;
#pragma unroll
        for (int d = 1; d < 64; d <<= 1) {
            int o = __shfl_up(sc, d);
            if (lane >= d) sc += o;
        }
        if (lane == 63) wsum[wid] = sc;
        __syncthreads();
        int woff = 0;
        for (int w = 0; w < wid; ++w) woff += wsum[w];
        int excl = woff + sc - s;
        if (base + 0 < n) row[base + 0] = excl;
        if (base + 1 < n) row[base + 1] = excl + v0;
        if (base + 2 < n) row[base + 2] = excl + v0 + v1i;
        if (base + 3 < n) row[base + 3] = excl + v0 + v1i + v2;
        if (t == 255) {
            bsum[b] = woff + sc;
            __threadfence();
            lastBlk = (atomicAdd(ctr, 1) == NBS - 1);
        }
        __syncthreads();
        if (lastBlk && t < 64) {
            __threadfence();
            int v = (t < NBS) ? ((volatile int*)bsum)[t] : 0;
            int sc2 = v;
#pragma unroll
            for (int d = 1; d < 64; d <<= 1) {
                int o = __shfl_up(sc2, d);
                if (t >= d) sc2 += o;
            }
            boff[t] = sc2 - v; // exclusive block offset
            if (t == (N_NODES >> 10)) row[N_NODES] = N_EDGES - (sc2 - v);
        }
        return;
    }
    // ---- gemm half ----
    int w = threadIdx.x >> 6;
    int l = threadIdx.x & 63;
    int rb = blockIdx.x * 32;
    int lr = l & 15, lk = l >> 4;
    // stage x[rb..rb+32)[64] -> bf16 LDS xs[32][72] (coalesced, converted once)
    unsigned short* xs = (unsigned short*)smem;
    {
        int t = threadIdx.x;
        int r = rb + (t >> 3);
        if (r >= n) r = n - 1;
        int c = (t & 7) * 8;
        const float* xp = x + (size_t)r * 64 + c;
        float4 f0 = *(const float4*)xp;
        float4 f1 = *(const float4*)(xp + 4);
        unsigned short* dp = xs + (t >> 3) * 72 + c;
        dp[0] = f2bf(f0.x); dp[1] = f2bf(f0.y); dp[2] = f2bf(f0.z); dp[3] = f2bf(f0.w);
        dp[4] = f2bf(f1.x); dp[5] = f2bf(f1.y); dp[6] = f2bf(f1.z); dp[7] = f2bf(f1.w);
    }
    __syncthreads();
    f32x4 acc[2][8];
#pragma unroll
    for (int mt = 0; mt < 2; ++mt)
#pragma unroll
        for (int nt = 0; nt < 8; ++nt) acc[mt][nt] = (f32x4){0.f, 0.f, 0.f, 0.f};
#pragma unroll
    for (int ks = 0; ks < 2; ++ks) {
        bf16x8 a[2];
#pragma unroll
        for (int mt = 0; mt < 2; ++mt)
            a[mt] = *(const bf16x8*)(xs + (mt * 16 + lr) * 72 + ks * 32 + lk * 8);
#pragma unroll
        for (int nt = 0; nt < 8; ++nt) {
            bf16x8 b = *(const bf16x8*)(Wf1 + (size_t)((w * 8 + nt) * 1024 + ks * 512 + l * 8));
            acc[0][nt] = MFMA16(a[0], b, acc[0][nt], 0, 0, 0);
            acc[1][nt] = MFMA16(a[1], b, acc[1][nt], 0, 0, 0);
        }
    }
    __syncthreads(); // xs reads done; epilogue reuses smem
    const float* bptr = (w == 0) ? bq : (w == 1) ? bk : (w == 2) ? bv : bs;
    unsigned char* my = smem + w * 4352;
#pragma unroll
    for (int mt = 0; mt < 2; ++mt) {
        if (w == 1 || w == 2) { // k,v -> fp8 into interleaved kv8
            unsigned char* lb = my; // [16][144]
#pragma unroll
            for (int nt = 0; nt < 8; ++nt) {
                float bias = bptr[nt * 16 + lr];
#pragma unroll
                for (int i = 0; i < 4; ++i)
                    lb[(lk * 4 + i) * 144 + nt * 16 + lr] = f2fp8(acc[mt][nt][i] + bias);
            }
            int voff = (w == 2) ? 8 : 0; // v occupies the upper 8B of each 16B group
#pragma unroll
            for (int p = 0; p < 4; ++p) {
                int rl = p * 4 + lk;
                int r = rb + mt * 16 + rl;
                if (r < n) {
                    uint2 val = *(const uint2*)(lb + rl * 144 + lr * 8);
                    *(uint2*)(kv8 + (size_t)r * 256 + lr * 16 + voff) = val;
                }
            }
        } else {
            unsigned short* ls = (unsigned short*)my; // [16][136]
#pragma unroll
            for (int nt = 0; nt < 8; ++nt) {
                float bias = bptr[nt * 16 + lr];
#pragma unroll
                for (int i = 0; i < 4; ++i)
                    ls[(lk * 4 + i) * 136 + nt * 16 + lr] = f2bf(acc[mt][nt][i] + bias);
            }
            unsigned short* outp = (w == 0) ? qs1 : qs1 + 128;
#pragma unroll
            for (int p = 0; p < 4; ++p) {
                int rl = p * 4 + lk;
                int r = rb + mt * 16 + rl;
                if (r < n) {
                    uint4 val = *(const uint4*)(ls + rl * 136 + lr * 8);
                    *(uint4*)(outp + (size_t)r * 256 + lr * 8) = val;
                }
            }
        }
    }
}

// ---------------- scatter ----------------

__global__ void k_scat(const int* __restrict__ src, const int* __restrict__ dst,
                       const int* __restrict__ row, const int* __restrict__ boff,
                       const int* __restrict__ rank, int* __restrict__ col) {
    int e = blockIdx.x * 256 + threadIdx.x;
    int de = dst[e];
    col[row[de] + boff[de >> 10] + rank[e]] = src[e];
}

// ---------------- GEMM 2 (MFMA): h1b[N,128]bf16 @ {Wq,Wk,Wv,Ws}[128,32] + b ----------------
// LDS-staged epilogue; outputs: qs2[N][64] bf16 (q 0:32, s 32:64);
//                               k82[N][32] fp8; v2[N][32] bf16

__global__ __launch_bounds__(256) void k_gemm2m(
    const unsigned short* __restrict__ h1b, const unsigned short* __restrict__ Wf2,
    const float* __restrict__ bq, const float* __restrict__ bk,
    const float* __restrict__ bv, const float* __restrict__ bs,
    unsigned short* __restrict__ qs2, unsigned char* __restrict__ k82,
    unsigned short* __restrict__ v2, int n)
{
    __shared__ unsigned short lds[4][32][72]; // 18.4 KB
    int w = threadIdx.x >> 6;
    int l = threadIdx.x & 63;
    int half = w & 1;
    int rb = blockIdx.x * 64 + (w >> 1) * 32;
    int lr = l & 15, lk = l >> 4;
    f32x4 acc[2][4];
#pragma unroll
    for (int mt = 0; mt < 2; ++mt)
#pragma unroll
        for (int nt = 0; nt < 4; ++nt) acc[mt][nt] = (f32x4){0.f, 0.f, 0.f, 0.f};
#pragma unroll
    for (int ks = 0; ks < 4; ++ks) {
        bf16x8 a[2];
#pragma unroll
        for (int mt = 0; mt < 2; ++mt) {
            int r = rb + mt * 16 + lr;
            if (r >= n) r = n - 1;
            a[mt] = *(const bf16x8*)(h1b + (size_t)r * 128 + ks * 32 + lk * 8);
        }
#pragma unroll
        for (int nt = 0; nt < 4; ++nt) {
            int g = half * 4 + nt;
            bf16x8 b = *(const bf16x8*)(Wf2 + (size_t)((g * 4 + ks) * 512 + l * 8));
            acc[0][nt] = MFMA16(a[0], b, acc[0][nt], 0, 0, 0);
            acc[1][nt] = MFMA16(a[1], b, acc[1][nt], 0, 0, 0);
        }
    }
    // stage: half==0 waves hold q (lds cols 0..31) + k (32..63);
    //        half==1 waves hold v (0..31) + s (32..63)
#pragma unroll
    for (int nt = 0; nt < 4; ++nt) {
        int g = half * 4 + nt;
        int mat = g >> 1;
        int c = (g * 16 + lr) & 31;
        const float* bp = (mat == 0) ? bq : (mat == 1) ? bk : (mat == 2) ? bv : bs;
        float bias = bp[c];
#pragma unroll
        for (int mt = 0; mt < 2; ++mt)
#pragma unroll
            for (int i = 0; i < 4; ++i)
                lds[w][mt * 16 + lk * 4 + i][nt * 16 + lr] = f2bf(acc[mt][nt][i] + bias);
    }
    int rl8 = l >> 3, ci = (l & 7) * 4;
#pragma unroll
    for (int p = 0; p < 4; ++p) {
        int rl = p * 8 + rl8;
        int r = rb + rl;
        if (r < n) {
            uint2 va = *(const uint2*)&lds[w][rl][ci];
            uint2 vb = *(const uint2*)&lds[w][rl][32 + ci];
            if (half == 0) {
                *(uint2*)(qs2 + (size_t)r * 64 + ci) = va;              // q bf16
                unsigned pk =                                            // k -> fp8
                      (unsigned)f2fp8(__uint_as_float(vb.x << 16))
                    | ((unsigned)f2fp8(__uint_as_float(vb.x & 0xffff0000u)) << 8)
                    | ((unsigned)f2fp8(__uint_as_float(vb.y << 16)) << 16)
                    | ((unsigned)f2fp8(__uint_as_float(vb.y & 0xffff0000u)) << 24);
                *(unsigned*)(k82 + (size_t)r * 32 + ci) = pk;
            } else {
                *(uint2*)(v2 + (size_t)r * 32 + ci) = va;               // v bf16
                *(uint2*)(qs2 + (size_t)r * 64 + 32 + ci) = vb;         // s bf16
            }
        }
    }
}

// ---------------- Layer-1 attention aggregate (R11 form: measured floor) ----------------
// one wave per dst node; lane = slot(0-3)*16 + w(0-15); lane owns channels [w*8, w*8+8).
// 8 edges per iteration; ONE dwordx4 gather per edge-lane (k in .xy, v in .zw).

__global__ __launch_bounds__(256) void k_agg1(
    const unsigned short* __restrict__ qs1, const unsigned char* __restrict__ kv8,
    const int* __restrict__ row, const int* __restrict__ boff,
    const int* __restrict__ col, uint4* __restrict__ h1b, int n)
{
    int i = blockIdx.x * 4 + (threadIdx.x >> 6);
    if (i >= n) return;
    int lane = threadIdx.x & 63;
    int slot = lane >> 4, w = lane & 15;
    f32x2 q2[4];
    {
        uint4 qu = *(const uint4*)(qs1 + (size_t)i * 256 + w * 8);
        q2[0] = bfp2(qu.x); q2[1] = bfp2(qu.y); q2[2] = bfp2(qu.z); q2[3] = bfp2(qu.w);
    }
    f32x2 acc2[4] = {};
    float d = 0.f;
    int s = row[i] + boff[i >> 10];
    int e = row[i + 1] + boff[(i + 1) >> 10];
    for (int t = s; t < e; t += 8) {
        int ta = t + slot, tb = t + 4 + slot;
        bool va = ta < e, vb = tb < e;
        int ja = col[va ? ta : s];
        int jb = col[vb ? tb : s];
        uint4 A = *(const uint4*)(kv8 + (size_t)ja * 256 + w * 16);
        uint4 B = *(const uint4*)(kv8 + (size_t)jb * 256 + w * 16);
        f32x2 pa = CVT8(A.x, false) * q2[0];
        pa += CVT8(A.x, true)  * q2[1];
        pa += CVT8(A.y, false) * q2[2];
        pa += CVT8(A.y, true)  * q2[3];
        f32x2 pb = CVT8(B.x, false) * q2[0];
        pb += CVT8(B.x, true)  * q2[1];
        pb += CVT8(B.y, false) * q2[2];
        pb += CVT8(B.y, true)  * q2[3];
        float la = pa[0] + pa[1];
        float lb = pb[0] + pb[1];
        la += __shfl_xor(la, 1);  lb += __shfl_xor(lb, 1);
        la += __shfl_xor(la, 2);  lb += __shfl_xor(lb, 2);
        float wa = va ? __expf(la * SCALE) : 0.f;
        float wb = vb ? __expf(lb * SCALE) : 0.f;
        d += wa + wb;
        f32x2 wa2 = (f32x2){wa, wa};
        f32x2 wb2 = (f32x2){wb, wb};
        acc2[0] += wa2 * CVT8(A.z, false);
        acc2[1] += wa2 * CVT8(A.z, true);
        acc2[2] += wa2 * CVT8(A.w, false);
        acc2[3] += wa2 * CVT8(A.w, true);
        acc2[0] += wb2 * CVT8(B.z, false);
        acc2[1] += wb2 * CVT8(B.z, true);
        acc2[2] += wb2 * CVT8(B.w, false);
        acc2[3] += wb2 * CVT8(B.w, true);
    }
    float acc[8] = {acc2[0][0], acc2[0][1], acc2[1][0], acc2[1][1],
                    acc2[2][0], acc2[2][1], acc2[3][0], acc2[3][1]};
#pragma unroll
    for (int m = 16; m <= 32; m <<= 1) {
        d += __shfl_xor(d, m);
#pragma unroll
        for (int c = 0; c < 8; ++c) acc[c] += __shfl_xor(acc[c], m);
    }
    if (slot == 0) {
        float inv = (d > 0.f) ? 1.f / d : 0.f;
        uint4 su = *(const uint4*)(qs1 + (size_t)i * 256 + 128 + w * 8);
        f32x2 sv[4] = {bfp2(su.x), bfp2(su.y), bfp2(su.z), bfp2(su.w)};
        unsigned o[4];
#pragma unroll
        for (int p = 0; p < 4; ++p) {
            float rx = acc[2 * p] * inv + sv[p][0];
            float ry = acc[2 * p + 1] * inv + sv[p][1];
            rx = (rx > 0.f) ? rx : expm1f(rx); // ELU
            ry = (ry > 0.f) ? ry : expm1f(ry);
            o[p] = ((unsigned)f2bf(ry) << 16) | (unsigned)f2bf(rx);
        }
        h1b[(size_t)i * 16 + w] = make_uint4(o[0], o[1], o[2], o[3]);
    }
}

// ---------------- Layer-2 attention aggregate ----------------
// one wave per dst node; lane = slot(0-15)*4 + qr(0-3); 16 edges/iteration.
// k gathered as fp8 (8B/lane), v as bf16 (16B/lane).

__global__ __launch_bounds__(256) void k_agg2(
    const unsigned short* __restrict__ qs2, const unsigned char* __restrict__ k82,
    const unsigned short* __restrict__ v2,
    const int* __restrict__ row, const int* __restrict__ boff,
    const int* __restrict__ col, float* __restrict__ out, int n)
{
    int i = blockIdx.x * 4 + (threadIdx.x >> 6);
    if (i >= n) return;
    int lane = threadIdx.x & 63;
    int slot = lane >> 2, qr = lane & 3;
    f32x2 q2[4];
    {
        uint4 qu = *(const uint4*)(qs2 + (size_t)i * 64 + qr * 8);
        q2[0] = bfp2(qu.x); q2[1] = bfp2(qu.y); q2[2] = bfp2(qu.z); q2[3] = bfp2(qu.w);
    }
    f32x2 acc2[4] = {};
    float d = 0.f;
    int s = row[i] + boff[i >> 10];
    int e = row[i + 1] + boff[(i + 1) >> 10];
    for (int t = s; t < e; t += 16) {
        int te = t + slot;
        bool va = te < e;
        int j = col[va ? te : s];
        uint2 ku = *(const uint2*)(k82 + (size_t)j * 32 + qr * 8);
        uint4 vu = *(const uint4*)(v2 + (size_t)j * 32 + qr * 8);
        f32x2 pp = CVT8(ku.x, false) * q2[0];
        pp += CVT8(ku.x, true)  * q2[1];
        pp += CVT8(ku.y, false) * q2[2];
        pp += CVT8(ku.y, true)  * q2[3];
        float lg = pp[0] + pp[1];
        lg += __shfl_xor(lg, 1);
        lg += __shfl_xor(lg, 2);
        float wv = va ? __expf(lg * SCALE) : 0.f;
        d += wv;
        f32x2 w2 = (f32x2){wv, wv};
        acc2[0] += w2 * bfp2(vu.x);
        acc2[1] += w2 * bfp2(vu.y);
        acc2[2] += w2 * bfp2(vu.z);
        acc2[3] += w2 * bfp2(vu.w);
    }
    float acc[8] = {acc2[0][0], acc2[0][1], acc2[1][0], acc2[1][1],
                    acc2[2][0], acc2[2][1], acc2[3][0], acc2[3][1]};
#pragma unroll
    for (int m = 4; m <= 32; m <<= 1) {
        d += __shfl_xor(d, m);
#pragma unroll
        for (int c = 0; c < 8; ++c) acc[c] += __shfl_xor(acc[c], m);
    }
    if (slot == 0) {
        float inv = (d > 0.f) ? 1.f / d : 0.f;
        uint4 su = *(const uint4*)(qs2 + (size_t)i * 64 + 32 + qr * 8);
        f32x2 sv[4] = {bfp2(su.x), bfp2(su.y), bfp2(su.z), bfp2(su.w)};
        float4 o0, o1;
        o0.x = acc[0] * inv + sv[0][0];
        o0.y = acc[1] * inv + sv[0][1];
        o0.z = acc[2] * inv + sv[1][0];
        o0.w = acc[3] * inv + sv[1][1];
        o1.x = acc[4] * inv + sv[2][0];
        o1.y = acc[5] * inv + sv[2][1];
        o1.z = acc[6] * inv + sv[3][0];
        o1.w = acc[7] * inv + sv[3][1];
        *(float4*)&out[(size_t)i * 32 + qr * 8] = o0;
        *(float4*)&out[(size_t)i * 32 + qr * 8 + 4] = o1;
    }
}

// ---------------- launch ----------------

extern "C" void kernel_launch(void* const* d_in, const int* in_sizes, int n_in,
                              void* d_out, int out_size, void* d_ws, size_t ws_size,
                              hipStream_t stream)
{
    const int N = N_NODES, E = N_EDGES;
    const float* x   = (const float*)d_in[0];
    const int* edge  = (const int*)d_in[1];
    const int* src   = edge;       // edge_index[0]
    const int* dst   = edge + E;   // edge_index[1]
    const float* Wq1 = (const float*)d_in[2];  const float* bq1 = (const float*)d_in[3];
    const float* Wk1 = (const float*)d_in[4];  const float* bk1 = (const float*)d_in[5];
    const float* Wv1 = (const float*)d_in[6];  const float* bv1 = (const float*)d_in[7];
    const float* Ws1 = (const float*)d_in[8];  const float* bs1 = (const float*)d_in[9];
    const float* Wq2 = (const float*)d_in[10]; const float* bq2 = (const float*)d_in[11];
    const float* Wk2 = (const float*)d_in[12]; const float* bk2 = (const float*)d_in[13];
    const float* Wv2 = (const float*)d_in[14]; const float* bv2 = (const float*)d_in[15];
    const float* Ws2 = (const float*)d_in[16]; const float* bs2 = (const float*)d_in[17];

    char* ws = (char*)d_ws;
    size_t off = 0;
    auto alloc = [&](size_t bytes) -> void* {
        void* p = ws + off;
        off += (bytes + 255) & ~(size_t)255;
        return p;
    };
    unsigned short* qs1 = (unsigned short*)alloc((size_t)N * 256 * 2); // 25.6 MB
    unsigned char*  kv8 = (unsigned char*)alloc((size_t)N * 256);      // 12.8 MB (k,v interleaved fp8)
    unsigned short* h1b = (unsigned short*)alloc((size_t)N * 128 * 2); // 12.8 MB
    unsigned short* qs2 = (unsigned short*)alloc((size_t)N * 64 * 2);  //  6.4 MB
    unsigned char*  k82 = (unsigned char*)alloc((size_t)N * 32);       //  1.6 MB (fp8 k2)
    unsigned short* v2  = (unsigned short*)alloc((size_t)N * 32 * 2);  //  3.2 MB (bf16 v2)
    unsigned short* Wf1 = (unsigned short*)alloc(32768 * 2);
    unsigned short* Wf2 = (unsigned short*)alloc(16384 * 2);
    int* row_ptr  = (int*)alloc((size_t)(N + 1) * 4);
    int* cnt      = (int*)alloc((size_t)(N + 64) * 4); // cnt[N] + ctr
    int* ctr      = cnt + N;
    int* rank     = (int*)alloc((size_t)E * 4);
    int* colb     = (int*)alloc((size_t)E * 4);
    int* bsum     = (int*)alloc(64 * 4);
    int* boff     = (int*)alloc(64 * 4);

    hipMemsetAsync(cnt, 0, (size_t)(N + 64) * 4, stream);
    k_ph<<<HB + 192, 256, 0, stream>>>(dst, cnt, rank,
                                       Wq1, Wk1, Wv1, Ws1, Wq2, Wk2, Wv2, Ws2,
                                       Wf1, Wf2);
    k_gs<<<GB1 + NBS, 256, 0, stream>>>(cnt, row_ptr, bsum, boff, ctr,
                                        x, Wf1, bq1, bk1, bv1, bs1, qs1, kv8, N);
    k_scat<<<HB, 256, 0, stream>>>(src, dst, row_ptr, boff, rank, colb);
    k_agg1<<<(N + 3) / 4, 256, 0, stream>>>(qs1, kv8, row_ptr, boff, colb, (uint4*)h1b, N);
    k_gemm2m<<<(N + 63) / 64, 256, 0, stream>>>(h1b, Wf2, bq2, bk2, bv2, bs2, qs2, k82, v2, N);
    k_agg2<<<(N + 3) / 4, 256, 0, stream>>>(qs2, k82, v2, row_ptr, boff, colb, (float*)d_out, N);
}

// Round 14
// 154.879 us; speedup vs baseline: 1.1485x; 1.0153x over previous
//
#include <hip/hip_runtime.h>
#include <hip/hip_bf16.h>
#include <hip/hip_fp8.h>

#define N_NODES 50000
#define N_EDGES 800000
#define HB 3125   // hist/scatter blocks: 800000/256
#define GB1 1563  // gemm1 blocks: ceil(50000/32)
#define NBS 49    // scan blocks: ceil(50000/1024)

static constexpr float SCALE = 0.17677669529663687f; // 1/sqrt(32)

typedef __attribute__((ext_vector_type(8))) short bf16x8;
typedef __attribute__((ext_vector_type(4))) float f32x4;
typedef __attribute__((ext_vector_type(2))) float f32x2;
#define MFMA16 __builtin_amdgcn_mfma_f32_16x16x32_bf16
#define CVT8 __builtin_amdgcn_cvt_pk_f32_fp8

static __device__ inline unsigned short f2bf(float f) {
    __hip_bfloat16 h = __float2bfloat16(f);
    return __builtin_bit_cast(unsigned short, h);
}
static __device__ inline unsigned char f2fp8(float f) {
    __hip_fp8_e4m3 h(f); // OCP e4m3fn, RNE
    return __builtin_bit_cast(unsigned char, h);
}
// packed pair of bf16 (one u32) -> f32x2
static __device__ inline f32x2 bfp2(unsigned u) {
    f32x2 r;
    r[0] = __uint_as_float(u << 16);
    r[1] = __uint_as_float(u & 0xffff0000u);
    return r;
}

// ---------------- D1: weight fragments + cnt/ctr zero (replaces memset) ----------------
// Fragment convention (consistent for A and B, so exact HW k-order is irrelevant):
//   lane l, elem j  <->  k = ks*32 + (l>>4)*8 + j ;  col = nt*16 + (l&15)

__global__ __launch_bounds__(256) void k_wf(
    const float* __restrict__ Wq1, const float* __restrict__ Wk1,
    const float* __restrict__ Wv1, const float* __restrict__ Ws1,
    const float* __restrict__ Wq2, const float* __restrict__ Wk2,
    const float* __restrict__ Wv2, const float* __restrict__ Ws2,
    unsigned short* __restrict__ Wf1, unsigned short* __restrict__ Wf2,
    int* __restrict__ cnt)
{
    int id = blockIdx.x * 256 + threadIdx.x;
    if (id < N_NODES + 64) cnt[id] = 0;  // cnt[N] + ctr tail
    if (id < 32768) {
        int j = id & 7, l = (id >> 3) & 63, ks = (id >> 9) & 1, nt = (id >> 10) & 7, m = (id >> 13) & 3;
        const float* W = (m == 0) ? Wq1 : (m == 1) ? Wk1 : (m == 2) ? Wv1 : Ws1;
        int k = ks * 32 + ((l >> 4) << 3) + j;
        int c = nt * 16 + (l & 15);
        Wf1[id] = f2bf(W[k * 128 + c]);
    } else if (id < 49152) {
        int id2 = id - 32768;
        int j = id2 & 7, l = (id2 >> 3) & 63, ks = (id2 >> 9) & 3, g = (id2 >> 11) & 7;
        int m = g >> 1, t = g & 1;
        const float* W = (m == 0) ? Wq2 : (m == 1) ? Wk2 : (m == 2) ? Wv2 : Ws2;
        int k = ks * 32 + ((l >> 4) << 3) + j;
        int c = t * 16 + (l & 15);
        Wf2[id2] = f2bf(W[k * 32 + c]);
    }
}

// ---------------- D2: hist (blocks 0..HB) || GEMM1 (blocks HB..HB+GB1) ----------------
// hist blocks first so the scan dependency clears early; both halves independent.
// GEMM1 (MFMA): x staged once per block into LDS as bf16; LDS 17.4KB -> 9 blk/CU
// (>= the 8-block wave cap, so the hist half is NOT occupancy-throttled — R8 lesson).
// outputs: qs1[N][256] bf16 (q 0:128, s 128:256);
//          kv8[N][256 bytes] fp8 interleaved: group w (0..15): k at byte w*16, v at w*16+8.

__global__ __launch_bounds__(256) void k_hg(
    const int* __restrict__ dst, int* __restrict__ cnt, int* __restrict__ rank,
    const float* __restrict__ x, const unsigned short* __restrict__ Wf1,
    const float* __restrict__ bq, const float* __restrict__ bk,
    const float* __restrict__ bv, const float* __restrict__ bs,
    unsigned short* __restrict__ qs1, unsigned char* __restrict__ kv8, int n)
{
    __shared__ unsigned char smem[4 * 4352]; // union: xs[32][72]bf16 (4.6KB) then epilogue 4x4352B
    if (blockIdx.x < HB) {
        int e = blockIdx.x * 256 + threadIdx.x; // E exact multiple of 256
        rank[e] = atomicAdd(&cnt[dst[e]], 1);
        return;
    }
    // ---- gemm half ----
    int w = threadIdx.x >> 6;
    int l = threadIdx.x & 63;
    int rb = (blockIdx.x - HB) * 32;
    int lr = l & 15, lk = l >> 4;
    // stage x[rb..rb+32)[64] -> bf16 LDS xs[32][72] (coalesced, converted once)
    unsigned short* xs = (unsigned short*)smem;
    {
        int t = threadIdx.x;
        int r = rb + (t >> 3);
        if (r >= n) r = n - 1;
        int c = (t & 7) * 8;
        const float* xp = x + (size_t)r * 64 + c;
        float4 f0 = *(const float4*)xp;
        float4 f1 = *(const float4*)(xp + 4);
        unsigned short* dp = xs + (t >> 3) * 72 + c;
        dp[0] = f2bf(f0.x); dp[1] = f2bf(f0.y); dp[2] = f2bf(f0.z); dp[3] = f2bf(f0.w);
        dp[4] = f2bf(f1.x); dp[5] = f2bf(f1.y); dp[6] = f2bf(f1.z); dp[7] = f2bf(f1.w);
    }
    __syncthreads();
    f32x4 acc[2][8];
#pragma unroll
    for (int mt = 0; mt < 2; ++mt)
#pragma unroll
        for (int nt = 0; nt < 8; ++nt) acc[mt][nt] = (f32x4){0.f, 0.f, 0.f, 0.f};
#pragma unroll
    for (int ks = 0; ks < 2; ++ks) {
        bf16x8 a[2];
#pragma unroll
        for (int mt = 0; mt < 2; ++mt)
            a[mt] = *(const bf16x8*)(xs + (mt * 16 + lr) * 72 + ks * 32 + lk * 8);
#pragma unroll
        for (int nt = 0; nt < 8; ++nt) {
            bf16x8 b = *(const bf16x8*)(Wf1 + (size_t)((w * 8 + nt) * 1024 + ks * 512 + l * 8));
            acc[0][nt] = MFMA16(a[0], b, acc[0][nt], 0, 0, 0);
            acc[1][nt] = MFMA16(a[1], b, acc[1][nt], 0, 0, 0);
        }
    }
    __syncthreads(); // xs reads done; epilogue reuses smem
    const float* bptr = (w == 0) ? bq : (w == 1) ? bk : (w == 2) ? bv : bs;
    unsigned char* my = smem + w * 4352;
#pragma unroll
    for (int mt = 0; mt < 2; ++mt) {
        if (w == 1 || w == 2) { // k,v -> fp8 into interleaved kv8
            unsigned char* lb = my; // [16][144]
#pragma unroll
            for (int nt = 0; nt < 8; ++nt) {
                float bias = bptr[nt * 16 + lr];
#pragma unroll
                for (int i = 0; i < 4; ++i)
                    lb[(lk * 4 + i) * 144 + nt * 16 + lr] = f2fp8(acc[mt][nt][i] + bias);
            }
            int voff = (w == 2) ? 8 : 0; // v occupies the upper 8B of each 16B group
#pragma unroll
            for (int p = 0; p < 4; ++p) {
                int rl = p * 4 + lk;
                int r = rb + mt * 16 + rl;
                if (r < n) {
                    uint2 val = *(const uint2*)(lb + rl * 144 + lr * 8);
                    *(uint2*)(kv8 + (size_t)r * 256 + lr * 16 + voff) = val;
                }
            }
        } else {
            unsigned short* ls = (unsigned short*)my; // [16][136]
#pragma unroll
            for (int nt = 0; nt < 8; ++nt) {
                float bias = bptr[nt * 16 + lr];
#pragma unroll
                for (int i = 0; i < 4; ++i)
                    ls[(lk * 4 + i) * 136 + nt * 16 + lr] = f2bf(acc[mt][nt][i] + bias);
            }
            unsigned short* outp = (w == 0) ? qs1 : qs1 + 128;
#pragma unroll
            for (int p = 0; p < 4; ++p) {
                int rl = p * 4 + lk;
                int r = rb + mt * 16 + rl;
                if (r < n) {
                    uint4 val = *(const uint4*)(ls + rl * 136 + lr * 8);
                    *(uint4*)(outp + (size_t)r * 256 + lr * 8) = val;
                }
            }
        }
    }
}

// ---------------- D3: fused scan (standalone, 49 blocks) ----------------

__global__ __launch_bounds__(256) void k_scan(const int* __restrict__ cnt,
                                              int* __restrict__ row,
                                              int* __restrict__ bsum,
                                              int* __restrict__ boff,
                                              int* __restrict__ ctr, int n) {
    __shared__ int wsum[4];
    __shared__ int lastBlk;
    int t = threadIdx.x;
    int base = blockIdx.x * 1024 + t * 4;
    int v0 = (base + 0 < n) ? cnt[base + 0] : 0;
    int v1i = (base + 1 < n) ? cnt[base + 1] : 0;
    int v2 = (base + 2 < n) ? cnt[base + 2] : 0;
    int v3 = (base + 3 < n) ? cnt[base + 3] : 0;
    int s = v0 + v1i + v2 + v3;
    int lane = t & 63, wid = t >> 6;
    int sc = s;
#pragma unroll
    for (int d = 1; d < 64; d <<= 1) {
        int o = __shfl_up(sc, d);
        if (lane >= d) sc += o;
    }
    if (lane == 63) wsum[wid] = sc;
    __syncthreads();
    int woff = 0;
    for (int w = 0; w < wid; ++w) woff += wsum[w];
    int excl = woff + sc - s;
    if (base + 0 < n) row[base + 0] = excl;
    if (base + 1 < n) row[base + 1] = excl + v0;
    if (base + 2 < n) row[base + 2] = excl + v0 + v1i;
    if (base + 3 < n) row[base + 3] = excl + v0 + v1i + v2;
    if (t == 255) {
        bsum[blockIdx.x] = woff + sc;
        __threadfence();
        lastBlk = (atomicAdd(ctr, 1) == NBS - 1);
    }
    __syncthreads();
    if (lastBlk && t < 64) {
        __threadfence();
        int v = (t < NBS) ? ((volatile int*)bsum)[t] : 0;
        int sc2 = v;
#pragma unroll
        for (int d = 1; d < 64; d <<= 1) {
            int o = __shfl_up(sc2, d);
            if (t >= d) sc2 += o;
        }
        boff[t] = sc2 - v; // exclusive block offset
        if (t == (N_NODES >> 10)) row[N_NODES] = N_EDGES - (sc2 - v);
    }
}

// ---------------- scatter ----------------

__global__ void k_scat(const int* __restrict__ src, const int* __restrict__ dst,
                       const int* __restrict__ row, const int* __restrict__ boff,
                       const int* __restrict__ rank, int* __restrict__ col) {
    int e = blockIdx.x * 256 + threadIdx.x;
    int de = dst[e];
    col[row[de] + boff[de >> 10] + rank[e]] = src[e];
}

// ---------------- GEMM 2 (MFMA): h1b[N,128]bf16 @ {Wq,Wk,Wv,Ws}[128,32] + b ----------------
// LDS-staged epilogue; outputs: qs2[N][64] bf16 (q 0:32, s 32:64);
//                               k82[N][32] fp8; v2[N][32] bf16

__global__ __launch_bounds__(256) void k_gemm2m(
    const unsigned short* __restrict__ h1b, const unsigned short* __restrict__ Wf2,
    const float* __restrict__ bq, const float* __restrict__ bk,
    const float* __restrict__ bv, const float* __restrict__ bs,
    unsigned short* __restrict__ qs2, unsigned char* __restrict__ k82,
    unsigned short* __restrict__ v2, int n)
{
    __shared__ unsigned short lds[4][32][72]; // 18.4 KB
    int w = threadIdx.x >> 6;
    int l = threadIdx.x & 63;
    int half = w & 1;
    int rb = blockIdx.x * 64 + (w >> 1) * 32;
    int lr = l & 15, lk = l >> 4;
    f32x4 acc[2][4];
#pragma unroll
    for (int mt = 0; mt < 2; ++mt)
#pragma unroll
        for (int nt = 0; nt < 4; ++nt) acc[mt][nt] = (f32x4){0.f, 0.f, 0.f, 0.f};
#pragma unroll
    for (int ks = 0; ks < 4; ++ks) {
        bf16x8 a[2];
#pragma unroll
        for (int mt = 0; mt < 2; ++mt) {
            int r = rb + mt * 16 + lr;
            if (r >= n) r = n - 1;
            a[mt] = *(const bf16x8*)(h1b + (size_t)r * 128 + ks * 32 + lk * 8);
        }
#pragma unroll
        for (int nt = 0; nt < 4; ++nt) {
            int g = half * 4 + nt;
            bf16x8 b = *(const bf16x8*)(Wf2 + (size_t)((g * 4 + ks) * 512 + l * 8));
            acc[0][nt] = MFMA16(a[0], b, acc[0][nt], 0, 0, 0);
            acc[1][nt] = MFMA16(a[1], b, acc[1][nt], 0, 0, 0);
        }
    }
    // stage: half==0 waves hold q (lds cols 0..31) + k (32..63);
    //        half==1 waves hold v (0..31) + s (32..63)
#pragma unroll
    for (int nt = 0; nt < 4; ++nt) {
        int g = half * 4 + nt;
        int mat = g >> 1;
        int c = (g * 16 + lr) & 31;
        const float* bp = (mat == 0) ? bq : (mat == 1) ? bk : (mat == 2) ? bv : bs;
        float bias = bp[c];
#pragma unroll
        for (int mt = 0; mt < 2; ++mt)
#pragma unroll
            for (int i = 0; i < 4; ++i)
                lds[w][mt * 16 + lk * 4 + i][nt * 16 + lr] = f2bf(acc[mt][nt][i] + bias);
    }
    int rl8 = l >> 3, ci = (l & 7) * 4;
#pragma unroll
    for (int p = 0; p < 4; ++p) {
        int rl = p * 8 + rl8;
        int r = rb + rl;
        if (r < n) {
            uint2 va = *(const uint2*)&lds[w][rl][ci];
            uint2 vb = *(const uint2*)&lds[w][rl][32 + ci];
            if (half == 0) {
                *(uint2*)(qs2 + (size_t)r * 64 + ci) = va;              // q bf16
                unsigned pk =                                            // k -> fp8
                      (unsigned)f2fp8(__uint_as_float(vb.x << 16))
                    | ((unsigned)f2fp8(__uint_as_float(vb.x & 0xffff0000u)) << 8)
                    | ((unsigned)f2fp8(__uint_as_float(vb.y << 16)) << 16)
                    | ((unsigned)f2fp8(__uint_as_float(vb.y & 0xffff0000u)) << 24);
                *(unsigned*)(k82 + (size_t)r * 32 + ci) = pk;
            } else {
                *(uint2*)(v2 + (size_t)r * 32 + ci) = va;               // v bf16
                *(uint2*)(qs2 + (size_t)r * 64 + 32 + ci) = vb;         // s bf16
            }
        }
    }
}

// ---------------- Layer-1 attention aggregate (measured floor: do not touch) ----------------
// one wave per dst node; lane = slot(0-3)*16 + w(0-15); lane owns channels [w*8, w*8+8).
// 8 edges per iteration; ONE dwordx4 gather per edge-lane (k in .xy, v in .zw).

__global__ __launch_bounds__(256) void k_agg1(
    const unsigned short* __restrict__ qs1, const unsigned char* __restrict__ kv8,
    const int* __restrict__ row, const int* __restrict__ boff,
    const int* __restrict__ col, uint4* __restrict__ h1b, int n)
{
    int i = blockIdx.x * 4 + (threadIdx.x >> 6);
    if (i >= n) return;
    int lane = threadIdx.x & 63;
    int slot = lane >> 4, w = lane & 15;
    f32x2 q2[4];
    {
        uint4 qu = *(const uint4*)(qs1 + (size_t)i * 256 + w * 8);
        q2[0] = bfp2(qu.x); q2[1] = bfp2(qu.y); q2[2] = bfp2(qu.z); q2[3] = bfp2(qu.w);
    }
    f32x2 acc2[4] = {};
    float d = 0.f;
    int s = row[i] + boff[i >> 10];
    int e = row[i + 1] + boff[(i + 1) >> 10];
    for (int t = s; t < e; t += 8) {
        int ta = t + slot, tb = t + 4 + slot;
        bool va = ta < e, vb = tb < e;
        int ja = col[va ? ta : s];
        int jb = col[vb ? tb : s];
        uint4 A = *(const uint4*)(kv8 + (size_t)ja * 256 + w * 16);
        uint4 B = *(const uint4*)(kv8 + (size_t)jb * 256 + w * 16);
        f32x2 pa = CVT8(A.x, false) * q2[0];
        pa += CVT8(A.x, true)  * q2[1];
        pa += CVT8(A.y, false) * q2[2];
        pa += CVT8(A.y, true)  * q2[3];
        f32x2 pb = CVT8(B.x, false) * q2[0];
        pb += CVT8(B.x, true)  * q2[1];
        pb += CVT8(B.y, false) * q2[2];
        pb += CVT8(B.y, true)  * q2[3];
        float la = pa[0] + pa[1];
        float lb = pb[0] + pb[1];
        la += __shfl_xor(la, 1);  lb += __shfl_xor(lb, 1);
        la += __shfl_xor(la, 2);  lb += __shfl_xor(lb, 2);
        float wa = va ? __expf(la * SCALE) : 0.f;
        float wb = vb ? __expf(lb * SCALE) : 0.f;
        d += wa + wb;
        f32x2 wa2 = (f32x2){wa, wa};
        f32x2 wb2 = (f32x2){wb, wb};
        acc2[0] += wa2 * CVT8(A.z, false);
        acc2[1] += wa2 * CVT8(A.z, true);
        acc2[2] += wa2 * CVT8(A.w, false);
        acc2[3] += wa2 * CVT8(A.w, true);
        acc2[0] += wb2 * CVT8(B.z, false);
        acc2[1] += wb2 * CVT8(B.z, true);
        acc2[2] += wb2 * CVT8(B.w, false);
        acc2[3] += wb2 * CVT8(B.w, true);
    }
    float acc[8] = {acc2[0][0], acc2[0][1], acc2[1][0], acc2[1][1],
                    acc2[2][0], acc2[2][1], acc2[3][0], acc2[3][1]};
#pragma unroll
    for (int m = 16; m <= 32; m <<= 1) {
        d += __shfl_xor(d, m);
#pragma unroll
        for (int c = 0; c < 8; ++c) acc[c] += __shfl_xor(acc[c], m);
    }
    if (slot == 0) {
        float inv = (d > 0.f) ? 1.f / d : 0.f;
        uint4 su = *(const uint4*)(qs1 + (size_t)i * 256 + 128 + w * 8);
        f32x2 sv[4] = {bfp2(su.x), bfp2(su.y), bfp2(su.z), bfp2(su.w)};
        unsigned o[4];
#pragma unroll
        for (int p = 0; p < 4; ++p) {
            float rx = acc[2 * p] * inv + sv[p][0];
            float ry = acc[2 * p + 1] * inv + sv[p][1];
            rx = (rx > 0.f) ? rx : expm1f(rx); // ELU
            ry = (ry > 0.f) ? ry : expm1f(ry);
            o[p] = ((unsigned)f2bf(ry) << 16) | (unsigned)f2bf(rx);
        }
        h1b[(size_t)i * 16 + w] = make_uint4(o[0], o[1], o[2], o[3]);
    }
}

// ---------------- Layer-2 attention aggregate ----------------
// one wave per dst node; lane = slot(0-15)*4 + qr(0-3); 16 edges/iteration.
// k gathered as fp8 (8B/lane), v as bf16 (16B/lane).

__global__ __launch_bounds__(256) void k_agg2(
    const unsigned short* __restrict__ qs2, const unsigned char* __restrict__ k82,
    const unsigned short* __restrict__ v2,
    const int* __restrict__ row, const int* __restrict__ boff,
    const int* __restrict__ col, float* __restrict__ out, int n)
{
    int i = blockIdx.x * 4 + (threadIdx.x >> 6);
    if (i >= n) return;
    int lane = threadIdx.x & 63;
    int slot = lane >> 2, qr = lane & 3;
    f32x2 q2[4];
    {
        uint4 qu = *(const uint4*)(qs2 + (size_t)i * 64 + qr * 8);
        q2[0] = bfp2(qu.x); q2[1] = bfp2(qu.y); q2[2] = bfp2(qu.z); q2[3] = bfp2(qu.w);
    }
    f32x2 acc2[4] = {};
    float d = 0.f;
    int s = row[i] + boff[i >> 10];
    int e = row[i + 1] + boff[(i + 1) >> 10];
    for (int t = s; t < e; t += 16) {
        int te = t + slot;
        bool va = te < e;
        int j = col[va ? te : s];
        uint2 ku = *(const uint2*)(k82 + (size_t)j * 32 + qr * 8);
        uint4 vu = *(const uint4*)(v2 + (size_t)j * 32 + qr * 8);
        f32x2 pp = CVT8(ku.x, false) * q2[0];
        pp += CVT8(ku.x, true)  * q2[1];
        pp += CVT8(ku.y, false) * q2[2];
        pp += CVT8(ku.y, true)  * q2[3];
        float lg = pp[0] + pp[1];
        lg += __shfl_xor(lg, 1);
        lg += __shfl_xor(lg, 2);
        float wv = va ? __expf(lg * SCALE) : 0.f;
        d += wv;
        f32x2 w2 = (f32x2){wv, wv};
        acc2[0] += w2 * bfp2(vu.x);
        acc2[1] += w2 * bfp2(vu.y);
        acc2[2] += w2 * bfp2(vu.z);
        acc2[3] += w2 * bfp2(vu.w);
    }
    float acc[8] = {acc2[0][0], acc2[0][1], acc2[1][0], acc2[1][1],
                    acc2[2][0], acc2[2][1], acc2[3][0], acc2[3][1]};
#pragma unroll
    for (int m = 4; m <= 32; m <<= 1) {
        d += __shfl_xor(d, m);
#pragma unroll
        for (int c = 0; c < 8; ++c) acc[c] += __shfl_xor(acc[c], m);
    }
    if (slot == 0) {
        float inv = (d > 0.f) ? 1.f / d : 0.f;
        uint4 su = *(const uint4*)(qs2 + (size_t)i * 64 + 32 + qr * 8);
        f32x2 sv[4] = {bfp2(su.x), bfp2(su.y), bfp2(su.z), bfp2(su.w)};
        float4 o0, o1;
        o0.x = acc[0] * inv + sv[0][0];
        o0.y = acc[1] * inv + sv[0][1];
        o0.z = acc[2] * inv + sv[1][0];
        o0.w = acc[3] * inv + sv[1][1];
        o1.x = acc[4] * inv + sv[2][0];
        o1.y = acc[5] * inv + sv[2][1];
        o1.z = acc[6] * inv + sv[3][0];
        o1.w = acc[7] * inv + sv[3][1];
        *(float4*)&out[(size_t)i * 32 + qr * 8] = o0;
        *(float4*)&out[(size_t)i * 32 + qr * 8 + 4] = o1;
    }
}

// ---------------- launch ----------------

extern "C" void kernel_launch(void* const* d_in, const int* in_sizes, int n_in,
                              void* d_out, int out_size, void* d_ws, size_t ws_size,
                              hipStream_t stream)
{
    const int N = N_NODES, E = N_EDGES;
    const float* x   = (const float*)d_in[0];
    const int* edge  = (const int*)d_in[1];
    const int* src   = edge;       // edge_index[0]
    const int* dst   = edge + E;   // edge_index[1]
    const float* Wq1 = (const float*)d_in[2];  const float* bq1 = (const float*)d_in[3];
    const float* Wk1 = (const float*)d_in[4];  const float* bk1 = (const float*)d_in[5];
    const float* Wv1 = (const float*)d_in[6];  const float* bv1 = (const float*)d_in[7];
    const float* Ws1 = (const float*)d_in[8];  const float* bs1 = (const float*)d_in[9];
    const float* Wq2 = (const float*)d_in[10]; const float* bq2 = (const float*)d_in[11];
    const float* Wk2 = (const float*)d_in[12]; const float* bk2 = (const float*)d_in[13];
    const float* Wv2 = (const float*)d_in[14]; const float* bv2 = (const float*)d_in[15];
    const float* Ws2 = (const float*)d_in[16]; const float* bs2 = (const float*)d_in[17];

    char* ws = (char*)d_ws;
    size_t off = 0;
    auto alloc = [&](size_t bytes) -> void* {
        void* p = ws + off;
        off += (bytes + 255) & ~(size_t)255;
        return p;
    };
    unsigned short* qs1 = (unsigned short*)alloc((size_t)N * 256 * 2); // 25.6 MB
    unsigned char*  kv8 = (unsigned char*)alloc((size_t)N * 256);      // 12.8 MB (k,v interleaved fp8)
    unsigned short* h1b = (unsigned short*)alloc((size_t)N * 128 * 2); // 12.8 MB
    unsigned short* qs2 = (unsigned short*)alloc((size_t)N * 64 * 2);  //  6.4 MB
    unsigned char*  k82 = (unsigned char*)alloc((size_t)N * 32);       //  1.6 MB (fp8 k2)
    unsigned short* v2  = (unsigned short*)alloc((size_t)N * 32 * 2);  //  3.2 MB (bf16 v2)
    unsigned short* Wf1 = (unsigned short*)alloc(32768 * 2);
    unsigned short* Wf2 = (unsigned short*)alloc(16384 * 2);
    int* row_ptr  = (int*)alloc((size_t)(N + 1) * 4);
    int* cnt      = (int*)alloc((size_t)(N + 64) * 4); // cnt[N] + ctr
    int* ctr      = cnt + N;
    int* rank     = (int*)alloc((size_t)E * 4);
    int* colb     = (int*)alloc((size_t)E * 4);
    int* bsum     = (int*)alloc(64 * 4);
    int* boff     = (int*)alloc(64 * 4);

    int WFB = (N + 64 + 255) / 256; // 196 blocks covers cnt zero + both wfrag ranges

    k_wf<<<WFB, 256, 0, stream>>>(Wq1, Wk1, Wv1, Ws1, Wq2, Wk2, Wv2, Ws2,
                                  Wf1, Wf2, cnt);
    k_hg<<<HB + GB1, 256, 0, stream>>>(dst, cnt, rank,
                                       x, Wf1, bq1, bk1, bv1, bs1, qs1, kv8, N);
    k_scan<<<NBS, 256, 0, stream>>>(cnt, row_ptr, bsum, boff, ctr, N);
    k_scat<<<HB, 256, 0, stream>>>(src, dst, row_ptr, boff, rank, colb);
    k_agg1<<<(N + 3) / 4, 256, 0, stream>>>(qs1, kv8, row_ptr, boff, colb, (uint4*)h1b, N);
    k_gemm2m<<<(N + 63) / 64, 256, 0, stream>>>(h1b, Wf2, bq2, bk2, bv2, bs2, qs2, k82, v2, N);
    k_agg2<<<(N + 3) / 4, 256, 0, stream>>>(qs2, k82, v2, row_ptr, boff, colb, (float*)d_out, N);
}

// Round 15
// 154.264 us; speedup vs baseline: 1.1531x; 1.0040x over previous
//
#include <hip/hip_runtime.h>
#include <hip/hip_bf16.h>
#include <hip/hip_fp8.h>

#define N_NODES 50000
#define N_EDGES 800000
#define HB 3125   // hist/scatter blocks: 800000/256
#define GB1 1563  // gemm1 blocks: ceil(50000/32)
#define NBS 49    // scan blocks: ceil(50000/1024)

static constexpr float SCALE = 0.17677669529663687f; // 1/sqrt(32)

typedef __attribute__((ext_vector_type(8))) short bf16x8;
typedef __attribute__((ext_vector_type(4))) float f32x4;
typedef __attribute__((ext_vector_type(2))) float f32x2;
#define MFMA16 __builtin_amdgcn_mfma_f32_16x16x32_bf16
#define CVT8 __builtin_amdgcn_cvt_pk_f32_fp8

static __device__ inline unsigned short f2bf(float f) {
    __hip_bfloat16 h = __float2bfloat16(f);
    return __builtin_bit_cast(unsigned short, h);
}
static __device__ inline unsigned char f2fp8(float f) {
    __hip_fp8_e4m3 h(f); // OCP e4m3fn, RNE
    return __builtin_bit_cast(unsigned char, h);
}
// packed pair of bf16 (one u32) -> f32x2
static __device__ inline f32x2 bfp2(unsigned u) {
    f32x2 r;
    r[0] = __uint_as_float(u << 16);
    r[1] = __uint_as_float(u & 0xffff0000u);
    return r;
}

// ---------------- D1: weight fragments + cnt/ctr zero ----------------
// Fragment convention (consistent for A and B, so exact HW k-order is irrelevant):
//   lane l, elem j  <->  k = ks*32 + (l>>4)*8 + j ;  col = nt*16 + (l&15)

__global__ __launch_bounds__(256) void k_wf(
    const float* __restrict__ Wq1, const float* __restrict__ Wk1,
    const float* __restrict__ Wv1, const float* __restrict__ Ws1,
    const float* __restrict__ Wq2, const float* __restrict__ Wk2,
    const float* __restrict__ Wv2, const float* __restrict__ Ws2,
    unsigned short* __restrict__ Wf1, unsigned short* __restrict__ Wf2,
    int* __restrict__ cnt)
{
    int id = blockIdx.x * 256 + threadIdx.x;
    if (id < N_NODES + 64) cnt[id] = 0;  // cnt[N] + ctr tail
    if (id < 32768) {
        int j = id & 7, l = (id >> 3) & 63, ks = (id >> 9) & 1, nt = (id >> 10) & 7, m = (id >> 13) & 3;
        const float* W = (m == 0) ? Wq1 : (m == 1) ? Wk1 : (m == 2) ? Wv1 : Ws1;
        int k = ks * 32 + ((l >> 4) << 3) + j;
        int c = nt * 16 + (l & 15);
        Wf1[id] = f2bf(W[k * 128 + c]);
    } else if (id < 49152) {
        int id2 = id - 32768;
        int j = id2 & 7, l = (id2 >> 3) & 63, ks = (id2 >> 9) & 3, g = (id2 >> 11) & 7;
        int m = g >> 1, t = g & 1;
        const float* W = (m == 0) ? Wq2 : (m == 1) ? Wk2 : (m == 2) ? Wv2 : Ws2;
        int k = ks * 32 + ((l >> 4) << 3) + j;
        int c = t * 16 + (l & 15);
        Wf2[id2] = f2bf(W[k * 32 + c]);
    }
}

// ---------------- D2: histogram (standalone: no LDS, minimal VGPR -> full occupancy) ----------------
// R14 lesson: fusing this with the 76-VGPR gemm halved its occupancy (latency-bound atomics).

__global__ void k_hist(const int* __restrict__ dst, int* __restrict__ cnt,
                       int* __restrict__ rank) {
    int e = blockIdx.x * 256 + threadIdx.x; // E exact multiple of 256
    rank[e] = atomicAdd(&cnt[dst[e]], 1);
}

// ---------------- D3: fused scan (standalone, 49 blocks) ----------------

__global__ __launch_bounds__(256) void k_scan(const int* __restrict__ cnt,
                                              int* __restrict__ row,
                                              int* __restrict__ bsum,
                                              int* __restrict__ boff,
                                              int* __restrict__ ctr, int n) {
    __shared__ int wsum[4];
    __shared__ int lastBlk;
    int t = threadIdx.x;
    int base = blockIdx.x * 1024 + t * 4;
    int v0 = (base + 0 < n) ? cnt[base + 0] : 0;
    int v1i = (base + 1 < n) ? cnt[base + 1] : 0;
    int v2 = (base + 2 < n) ? cnt[base + 2] : 0;
    int v3 = (base + 3 < n) ? cnt[base + 3] : 0;
    int s = v0 + v1i + v2 + v3;
    int lane = t & 63, wid = t >> 6;
    int sc = s;
#pragma unroll
    for (int d = 1; d < 64; d <<= 1) {
        int o = __shfl_up(sc, d);
        if (lane >= d) sc += o;
    }
    if (lane == 63) wsum[wid] = sc;
    __syncthreads();
    int woff = 0;
    for (int w = 0; w < wid; ++w) woff += wsum[w];
    int excl = woff + sc - s;
    if (base + 0 < n) row[base + 0] = excl;
    if (base + 1 < n) row[base + 1] = excl + v0;
    if (base + 2 < n) row[base + 2] = excl + v0 + v1i;
    if (base + 3 < n) row[base + 3] = excl + v0 + v1i + v2;
    if (t == 255) {
        bsum[blockIdx.x] = woff + sc;
        __threadfence();
        lastBlk = (atomicAdd(ctr, 1) == NBS - 1);
    }
    __syncthreads();
    if (lastBlk && t < 64) {
        __threadfence();
        int v = (t < NBS) ? ((volatile int*)bsum)[t] : 0;
        int sc2 = v;
#pragma unroll
        for (int d = 1; d < 64; d <<= 1) {
            int o = __shfl_up(sc2, d);
            if (t >= d) sc2 += o;
        }
        boff[t] = sc2 - v; // exclusive block offset
        if (t == (N_NODES >> 10)) row[N_NODES] = N_EDGES - (sc2 - v);
    }
}

// ---------------- D4: GEMM1 (blocks 0..GB1) || scatter (blocks GB1..GB1+HB) ----------------
// Scatter depends only on scan+rank (both complete); it hides under the longer gemm.
// Scatter's colb writes are L2-resident (3.2MB) -> throughput-bound, tolerant of the
// fused kernel's 16-waves/CU occupancy (unlike the latency-bound hist — R14 lesson).
// GEMM1 (MFMA): x staged once per block into LDS as bf16.
// outputs: qs1[N][256] bf16 (q 0:128, s 128:256);
//          kv8[N][256 bytes] fp8 interleaved: group w (0..15): k at byte w*16, v at w*16+8.

__global__ __launch_bounds__(256) void k_gsc(
    const int* __restrict__ src, const int* __restrict__ dst,
    const int* __restrict__ row, const int* __restrict__ boff,
    const int* __restrict__ rank, int* __restrict__ col,
    const float* __restrict__ x, const unsigned short* __restrict__ Wf1,
    const float* __restrict__ bq, const float* __restrict__ bk,
    const float* __restrict__ bv, const float* __restrict__ bs,
    unsigned short* __restrict__ qs1, unsigned char* __restrict__ kv8, int n)
{
    __shared__ unsigned char smem[4 * 4352]; // union: xs[32][72]bf16 (4.6KB) then epilogue 4x4352B
    if (blockIdx.x >= GB1) {
        int e = (blockIdx.x - GB1) * 256 + threadIdx.x;
        int de = dst[e];
        col[row[de] + boff[de >> 10] + rank[e]] = src[e];
        return;
    }
    // ---- gemm half ----
    int w = threadIdx.x >> 6;
    int l = threadIdx.x & 63;
    int rb = blockIdx.x * 32;
    int lr = l & 15, lk = l >> 4;
    // stage x[rb..rb+32)[64] -> bf16 LDS xs[32][72] (coalesced, converted once)
    unsigned short* xs = (unsigned short*)smem;
    {
        int t = threadIdx.x;
        int r = rb + (t >> 3);
        if (r >= n) r = n - 1;
        int c = (t & 7) * 8;
        const float* xp = x + (size_t)r * 64 + c;
        float4 f0 = *(const float4*)xp;
        float4 f1 = *(const float4*)(xp + 4);
        unsigned short* dp = xs + (t >> 3) * 72 + c;
        dp[0] = f2bf(f0.x); dp[1] = f2bf(f0.y); dp[2] = f2bf(f0.z); dp[3] = f2bf(f0.w);
        dp[4] = f2bf(f1.x); dp[5] = f2bf(f1.y); dp[6] = f2bf(f1.z); dp[7] = f2bf(f1.w);
    }
    __syncthreads();
    f32x4 acc[2][8];
#pragma unroll
    for (int mt = 0; mt < 2; ++mt)
#pragma unroll
        for (int nt = 0; nt < 8; ++nt) acc[mt][nt] = (f32x4){0.f, 0.f, 0.f, 0.f};
#pragma unroll
    for (int ks = 0; ks < 2; ++ks) {
        bf16x8 a[2];
#pragma unroll
        for (int mt = 0; mt < 2; ++mt)
            a[mt] = *(const bf16x8*)(xs + (mt * 16 + lr) * 72 + ks * 32 + lk * 8);
#pragma unroll
        for (int nt = 0; nt < 8; ++nt) {
            bf16x8 b = *(const bf16x8*)(Wf1 + (size_t)((w * 8 + nt) * 1024 + ks * 512 + l * 8));
            acc[0][nt] = MFMA16(a[0], b, acc[0][nt], 0, 0, 0);
            acc[1][nt] = MFMA16(a[1], b, acc[1][nt], 0, 0, 0);
        }
    }
    __syncthreads(); // xs reads done; epilogue reuses smem
    const float* bptr = (w == 0) ? bq : (w == 1) ? bk : (w == 2) ? bv : bs;
    unsigned char* my = smem + w * 4352;
#pragma unroll
    for (int mt = 0; mt < 2; ++mt) {
        if (w == 1 || w == 2) { // k,v -> fp8 into interleaved kv8
            unsigned char* lb = my; // [16][144]
#pragma unroll
            for (int nt = 0; nt < 8; ++nt) {
                float bias = bptr[nt * 16 + lr];
#pragma unroll
                for (int i = 0; i < 4; ++i)
                    lb[(lk * 4 + i) * 144 + nt * 16 + lr] = f2fp8(acc[mt][nt][i] + bias);
            }
            int voff = (w == 2) ? 8 : 0; // v occupies the upper 8B of each 16B group
#pragma unroll
            for (int p = 0; p < 4; ++p) {
                int rl = p * 4 + lk;
                int r = rb + mt * 16 + rl;
                if (r < n) {
                    uint2 val = *(const uint2*)(lb + rl * 144 + lr * 8);
                    *(uint2*)(kv8 + (size_t)r * 256 + lr * 16 + voff) = val;
                }
            }
        } else {
            unsigned short* ls = (unsigned short*)my; // [16][136]
#pragma unroll
            for (int nt = 0; nt < 8; ++nt) {
                float bias = bptr[nt * 16 + lr];
#pragma unroll
                for (int i = 0; i < 4; ++i)
                    ls[(lk * 4 + i) * 136 + nt * 16 + lr] = f2bf(acc[mt][nt][i] + bias);
            }
            unsigned short* outp = (w == 0) ? qs1 : qs1 + 128;
#pragma unroll
            for (int p = 0; p < 4; ++p) {
                int rl = p * 4 + lk;
                int r = rb + mt * 16 + rl;
                if (r < n) {
                    uint4 val = *(const uint4*)(ls + rl * 136 + lr * 8);
                    *(uint4*)(outp + (size_t)r * 256 + lr * 8) = val;
                }
            }
        }
    }
}

// ---------------- GEMM 2 (MFMA): h1b[N,128]bf16 @ {Wq,Wk,Wv,Ws}[128,32] + b ----------------
// LDS-staged epilogue; outputs: qs2[N][64] bf16 (q 0:32, s 32:64);
//                               k82[N][32] fp8; v2[N][32] bf16

__global__ __launch_bounds__(256) void k_gemm2m(
    const unsigned short* __restrict__ h1b, const unsigned short* __restrict__ Wf2,
    const float* __restrict__ bq, const float* __restrict__ bk,
    const float* __restrict__ bv, const float* __restrict__ bs,
    unsigned short* __restrict__ qs2, unsigned char* __restrict__ k82,
    unsigned short* __restrict__ v2, int n)
{
    __shared__ unsigned short lds[4][32][72]; // 18.4 KB
    int w = threadIdx.x >> 6;
    int l = threadIdx.x & 63;
    int half = w & 1;
    int rb = blockIdx.x * 64 + (w >> 1) * 32;
    int lr = l & 15, lk = l >> 4;
    f32x4 acc[2][4];
#pragma unroll
    for (int mt = 0; mt < 2; ++mt)
#pragma unroll
        for (int nt = 0; nt < 4; ++nt) acc[mt][nt] = (f32x4){0.f, 0.f, 0.f, 0.f};
#pragma unroll
    for (int ks = 0; ks < 4; ++ks) {
        bf16x8 a[2];
#pragma unroll
        for (int mt = 0; mt < 2; ++mt) {
            int r = rb + mt * 16 + lr;
            if (r >= n) r = n - 1;
            a[mt] = *(const bf16x8*)(h1b + (size_t)r * 128 + ks * 32 + lk * 8);
        }
#pragma unroll
        for (int nt = 0; nt < 4; ++nt) {
            int g = half * 4 + nt;
            bf16x8 b = *(const bf16x8*)(Wf2 + (size_t)((g * 4 + ks) * 512 + l * 8));
            acc[0][nt] = MFMA16(a[0], b, acc[0][nt], 0, 0, 0);
            acc[1][nt] = MFMA16(a[1], b, acc[1][nt], 0, 0, 0);
        }
    }
    // stage: half==0 waves hold q (lds cols 0..31) + k (32..63);
    //        half==1 waves hold v (0..31) + s (32..63)
#pragma unroll
    for (int nt = 0; nt < 4; ++nt) {
        int g = half * 4 + nt;
        int mat = g >> 1;
        int c = (g * 16 + lr) & 31;
        const float* bp = (mat == 0) ? bq : (mat == 1) ? bk : (mat == 2) ? bv : bs;
        float bias = bp[c];
#pragma unroll
        for (int mt = 0; mt < 2; ++mt)
#pragma unroll
            for (int i = 0; i < 4; ++i)
                lds[w][mt * 16 + lk * 4 + i][nt * 16 + lr] = f2bf(acc[mt][nt][i] + bias);
    }
    int rl8 = l >> 3, ci = (l & 7) * 4;
#pragma unroll
    for (int p = 0; p < 4; ++p) {
        int rl = p * 8 + rl8;
        int r = rb + rl;
        if (r < n) {
            uint2 va = *(const uint2*)&lds[w][rl][ci];
            uint2 vb = *(const uint2*)&lds[w][rl][32 + ci];
            if (half == 0) {
                *(uint2*)(qs2 + (size_t)r * 64 + ci) = va;              // q bf16
                unsigned pk =                                            // k -> fp8
                      (unsigned)f2fp8(__uint_as_float(vb.x << 16))
                    | ((unsigned)f2fp8(__uint_as_float(vb.x & 0xffff0000u)) << 8)
                    | ((unsigned)f2fp8(__uint_as_float(vb.y << 16)) << 16)
                    | ((unsigned)f2fp8(__uint_as_float(vb.y & 0xffff0000u)) << 24);
                *(unsigned*)(k82 + (size_t)r * 32 + ci) = pk;
            } else {
                *(uint2*)(v2 + (size_t)r * 32 + ci) = va;               // v bf16
                *(uint2*)(qs2 + (size_t)r * 64 + 32 + ci) = vb;         // s bf16
            }
        }
    }
}

// ---------------- Layer-1 attention aggregate (measured floor: do not touch) ----------------
// one wave per dst node; lane = slot(0-3)*16 + w(0-15); lane owns channels [w*8, w*8+8).
// 8 edges per iteration; ONE dwordx4 gather per edge-lane (k in .xy, v in .zw).

__global__ __launch_bounds__(256) void k_agg1(
    const unsigned short* __restrict__ qs1, const unsigned char* __restrict__ kv8,
    const int* __restrict__ row, const int* __restrict__ boff,
    const int* __restrict__ col, uint4* __restrict__ h1b, int n)
{
    int i = blockIdx.x * 4 + (threadIdx.x >> 6);
    if (i >= n) return;
    int lane = threadIdx.x & 63;
    int slot = lane >> 4, w = lane & 15;
    f32x2 q2[4];
    {
        uint4 qu = *(const uint4*)(qs1 + (size_t)i * 256 + w * 8);
        q2[0] = bfp2(qu.x); q2[1] = bfp2(qu.y); q2[2] = bfp2(qu.z); q2[3] = bfp2(qu.w);
    }
    f32x2 acc2[4] = {};
    float d = 0.f;
    int s = row[i] + boff[i >> 10];
    int e = row[i + 1] + boff[(i + 1) >> 10];
    for (int t = s; t < e; t += 8) {
        int ta = t + slot, tb = t + 4 + slot;
        bool va = ta < e, vb = tb < e;
        int ja = col[va ? ta : s];
        int jb = col[vb ? tb : s];
        uint4 A = *(const uint4*)(kv8 + (size_t)ja * 256 + w * 16);
        uint4 B = *(const uint4*)(kv8 + (size_t)jb * 256 + w * 16);
        f32x2 pa = CVT8(A.x, false) * q2[0];
        pa += CVT8(A.x, true)  * q2[1];
        pa += CVT8(A.y, false) * q2[2];
        pa += CVT8(A.y, true)  * q2[3];
        f32x2 pb = CVT8(B.x, false) * q2[0];
        pb += CVT8(B.x, true)  * q2[1];
        pb += CVT8(B.y, false) * q2[2];
        pb += CVT8(B.y, true)  * q2[3];
        float la = pa[0] + pa[1];
        float lb = pb[0] + pb[1];
        la += __shfl_xor(la, 1);  lb += __shfl_xor(lb, 1);
        la += __shfl_xor(la, 2);  lb += __shfl_xor(lb, 2);
        float wa = va ? __expf(la * SCALE) : 0.f;
        float wb = vb ? __expf(lb * SCALE) : 0.f;
        d += wa + wb;
        f32x2 wa2 = (f32x2){wa, wa};
        f32x2 wb2 = (f32x2){wb, wb};
        acc2[0] += wa2 * CVT8(A.z, false);
        acc2[1] += wa2 * CVT8(A.z, true);
        acc2[2] += wa2 * CVT8(A.w, false);
        acc2[3] += wa2 * CVT8(A.w, true);
        acc2[0] += wb2 * CVT8(B.z, false);
        acc2[1] += wb2 * CVT8(B.z, true);
        acc2[2] += wb2 * CVT8(B.w, false);
        acc2[3] += wb2 * CVT8(B.w, true);
    }
    float acc[8] = {acc2[0][0], acc2[0][1], acc2[1][0], acc2[1][1],
                    acc2[2][0], acc2[2][1], acc2[3][0], acc2[3][1]};
#pragma unroll
    for (int m = 16; m <= 32; m <<= 1) {
        d += __shfl_xor(d, m);
#pragma unroll
        for (int c = 0; c < 8; ++c) acc[c] += __shfl_xor(acc[c], m);
    }
    if (slot == 0) {
        float inv = (d > 0.f) ? 1.f / d : 0.f;
        uint4 su = *(const uint4*)(qs1 + (size_t)i * 256 + 128 + w * 8);
        f32x2 sv[4] = {bfp2(su.x), bfp2(su.y), bfp2(su.z), bfp2(su.w)};
        unsigned o[4];
#pragma unroll
        for (int p = 0; p < 4; ++p) {
            float rx = acc[2 * p] * inv + sv[p][0];
            float ry = acc[2 * p + 1] * inv + sv[p][1];
            rx = (rx > 0.f) ? rx : expm1f(rx); // ELU
            ry = (ry > 0.f) ? ry : expm1f(ry);
            o[p] = ((unsigned)f2bf(ry) << 16) | (unsigned)f2bf(rx);
        }
        h1b[(size_t)i * 16 + w] = make_uint4(o[0], o[1], o[2], o[3]);
    }
}

// ---------------- Layer-2 attention aggregate ----------------
// one wave per dst node; lane = slot(0-15)*4 + qr(0-3); 16 edges/iteration.
// k gathered as fp8 (8B/lane), v as bf16 (16B/lane).

__global__ __launch_bounds__(256) void k_agg2(
    const unsigned short* __restrict__ qs2, const unsigned char* __restrict__ k82,
    const unsigned short* __restrict__ v2,
    const int* __restrict__ row, const int* __restrict__ boff,
    const int* __restrict__ col, float* __restrict__ out, int n)
{
    int i = blockIdx.x * 4 + (threadIdx.x >> 6);
    if (i >= n) return;
    int lane = threadIdx.x & 63;
    int slot = lane >> 2, qr = lane & 3;
    f32x2 q2[4];
    {
        uint4 qu = *(const uint4*)(qs2 + (size_t)i * 64 + qr * 8);
        q2[0] = bfp2(qu.x); q2[1] = bfp2(qu.y); q2[2] = bfp2(qu.z); q2[3] = bfp2(qu.w);
    }
    f32x2 acc2[4] = {};
    float d = 0.f;
    int s = row[i] + boff[i >> 10];
    int e = row[i + 1] + boff[(i + 1) >> 10];
    for (int t = s; t < e; t += 16) {
        int te = t + slot;
        bool va = te < e;
        int j = col[va ? te : s];
        uint2 ku = *(const uint2*)(k82 + (size_t)j * 32 + qr * 8);
        uint4 vu = *(const uint4*)(v2 + (size_t)j * 32 + qr * 8);
        f32x2 pp = CVT8(ku.x, false) * q2[0];
        pp += CVT8(ku.x, true)  * q2[1];
        pp += CVT8(ku.y, false) * q2[2];
        pp += CVT8(ku.y, true)  * q2[3];
        float lg = pp[0] + pp[1];
        lg += __shfl_xor(lg, 1);
        lg += __shfl_xor(lg, 2);
        float wv = va ? __expf(lg * SCALE) : 0.f;
        d += wv;
        f32x2 w2 = (f32x2){wv, wv};
        acc2[0] += w2 * bfp2(vu.x);
        acc2[1] += w2 * bfp2(vu.y);
        acc2[2] += w2 * bfp2(vu.z);
        acc2[3] += w2 * bfp2(vu.w);
    }
    float acc[8] = {acc2[0][0], acc2[0][1], acc2[1][0], acc2[1][1],
                    acc2[2][0], acc2[2][1], acc2[3][0], acc2[3][1]};
#pragma unroll
    for (int m = 4; m <= 32; m <<= 1) {
        d += __shfl_xor(d, m);
#pragma unroll
        for (int c = 0; c < 8; ++c) acc[c] += __shfl_xor(acc[c], m);
    }
    if (slot == 0) {
        float inv = (d > 0.f) ? 1.f / d : 0.f;
        uint4 su = *(const uint4*)(qs2 + (size_t)i * 64 + 32 + qr * 8);
        f32x2 sv[4] = {bfp2(su.x), bfp2(su.y), bfp2(su.z), bfp2(su.w)};
        float4 o0, o1;
        o0.x = acc[0] * inv + sv[0][0];
        o0.y = acc[1] * inv + sv[0][1];
        o0.z = acc[2] * inv + sv[1][0];
        o0.w = acc[3] * inv + sv[1][1];
        o1.x = acc[4] * inv + sv[2][0];
        o1.y = acc[5] * inv + sv[2][1];
        o1.z = acc[6] * inv + sv[3][0];
        o1.w = acc[7] * inv + sv[3][1];
        *(float4*)&out[(size_t)i * 32 + qr * 8] = o0;
        *(float4*)&out[(size_t)i * 32 + qr * 8 + 4] = o1;
    }
}

// ---------------- launch ----------------

extern "C" void kernel_launch(void* const* d_in, const int* in_sizes, int n_in,
                              void* d_out, int out_size, void* d_ws, size_t ws_size,
                              hipStream_t stream)
{
    const int N = N_NODES, E = N_EDGES;
    const float* x   = (const float*)d_in[0];
    const int* edge  = (const int*)d_in[1];
    const int* src   = edge;       // edge_index[0]
    const int* dst   = edge + E;   // edge_index[1]
    const float* Wq1 = (const float*)d_in[2];  const float* bq1 = (const float*)d_in[3];
    const float* Wk1 = (const float*)d_in[4];  const float* bk1 = (const float*)d_in[5];
    const float* Wv1 = (const float*)d_in[6];  const float* bv1 = (const float*)d_in[7];
    const float* Ws1 = (const float*)d_in[8];  const float* bs1 = (const float*)d_in[9];
    const float* Wq2 = (const float*)d_in[10]; const float* bq2 = (const float*)d_in[11];
    const float* Wk2 = (const float*)d_in[12]; const float* bk2 = (const float*)d_in[13];
    const float* Wv2 = (const float*)d_in[14]; const float* bv2 = (const float*)d_in[15];
    const float* Ws2 = (const float*)d_in[16]; const float* bs2 = (const float*)d_in[17];

    char* ws = (char*)d_ws;
    size_t off = 0;
    auto alloc = [&](size_t bytes) -> void* {
        void* p = ws + off;
        off += (bytes + 255) & ~(size_t)255;
        return p;
    };
    unsigned short* qs1 = (unsigned short*)alloc((size_t)N * 256 * 2); // 25.6 MB
    unsigned char*  kv8 = (unsigned char*)alloc((size_t)N * 256);      // 12.8 MB (k,v interleaved fp8)
    unsigned short* h1b = (unsigned short*)alloc((size_t)N * 128 * 2); // 12.8 MB
    unsigned short* qs2 = (unsigned short*)alloc((size_t)N * 64 * 2);  //  6.4 MB
    unsigned char*  k82 = (unsigned char*)alloc((size_t)N * 32);       //  1.6 MB (fp8 k2)
    unsigned short* v2  = (unsigned short*)alloc((size_t)N * 32 * 2);  //  3.2 MB (bf16 v2)
    unsigned short* Wf1 = (unsigned short*)alloc(32768 * 2);
    unsigned short* Wf2 = (unsigned short*)alloc(16384 * 2);
    int* row_ptr  = (int*)alloc((size_t)(N + 1) * 4);
    int* cnt      = (int*)alloc((size_t)(N + 64) * 4); // cnt[N] + ctr
    int* ctr      = cnt + N;
    int* rank     = (int*)alloc((size_t)E * 4);
    int* colb     = (int*)alloc((size_t)E * 4);
    int* bsum     = (int*)alloc(64 * 4);
    int* boff     = (int*)alloc(64 * 4);

    int WFB = (N + 64 + 255) / 256; // 196 blocks covers cnt zero + both wfrag ranges

    k_wf<<<WFB, 256, 0, stream>>>(Wq1, Wk1, Wv1, Ws1, Wq2, Wk2, Wv2, Ws2,
                                  Wf1, Wf2, cnt);
    k_hist<<<HB, 256, 0, stream>>>(dst, cnt, rank);
    k_scan<<<NBS, 256, 0, stream>>>(cnt, row_ptr, bsum, boff, ctr, N);
    k_gsc<<<GB1 + HB, 256, 0, stream>>>(src, dst, row_ptr, boff, rank, colb,
                                        x, Wf1, bq1, bk1, bv1, bs1, qs1, kv8, N);
    k_agg1<<<(N + 3) / 4, 256, 0, stream>>>(qs1, kv8, row_ptr, boff, colb, (uint4*)h1b, N);
    k_gemm2m<<<(N + 63) / 64, 256, 0, stream>>>(h1b, Wf2, bq2, bk2, bv2, bs2, qs2, k82, v2, N);
    k_agg2<<<(N + 3) / 4, 256, 0, stream>>>(qs2, k82, v2, row_ptr, boff, colb, (float*)d_out, N);
}